// Round 11
// baseline (11428.354 us; speedup 1.0000x reference)
//
#include <hip/hip_runtime.h>
#include <hip/hip_bf16.h>

// ConvLSTM (2 layers) on MI355X. R22 = R21 (best, 1933us) + gate0 nt-merge (512-thr).
// R21 confirmed dead-K removal (CS=160 kept, x via Xtap tap-packed phase). Remaining
// stall: halo staged 4x per dispatch (per nt) and only 8 waves/CU (2/SIMD, LDS-capped).
// R22: 512-thread blocks cover 2 nt-halves -> grid 512 = 2 nth x 256 mt. Halo staged
// 2x not 4x (staging requests /2); residency 2 blocks x 8 waves = 16 waves/CU (4/SIMD)
// at same 61KB LDS, pinned by __launch_bounds__(512,4) (<=128 VGPR; R21 measured 128).
// 6 staging waves own one halo row each; waves 6,7 compute-only. Inner loop identical:
// R19 spread staging (<=1 DMA/wave/tap), 1-tap B prefetch, x-phase loads before DMAs.
// gate1 unchanged (R21 form). Kept: XCD stripe swizzle, tail-less DMA rows, zero page,
// P (B,64,64,160) fp16 [h0 0..127][h1 128..139][pad], 4-row M-tile, acc 8x4, tanhf.

typedef __attribute__((ext_vector_type(8))) short short8;
typedef __attribute__((ext_vector_type(4))) float float4v;

#define CS 160
#define KT0 1152          // gate0 K = 9*128 (pure h0)
#define KTOT 1440         // gate1 K = 9*160
#define RSTR 2560         // LDS halo row stride (shorts) = 5 * 64 lanes * 8
#define BSTR 10240        // gate1 LDS buffer stride (shorts) = 4 * RSTR
#define BSTR6 15360       // gate0 LDS buffer stride (shorts) = 6 * RSTR

__device__ __forceinline__ float sigf(float x) { return 1.f / (1.f + __expf(-x)); }
__device__ __forceinline__ short f2hs(float v) {
  _Float16 h = (_Float16)v;
  return *(short*)&h;
}
__device__ __forceinline__ float bs2f(short s) {
  __hip_bfloat16 h; *(short*)&h = s; return __bfloat162float(h);
}
__device__ __forceinline__ short f2bs(float v) {
  __hip_bfloat16 h = __float2bfloat16(v);
  return *(short*)&h;
}

// async 16B global->LDS; per-lane lds ptr must equal uniform_base + lane*16
__device__ __forceinline__ void async_ld16(const short* g, short* l) {
  __builtin_amdgcn_global_load_lds(
      (const __attribute__((address_space(1))) unsigned int*)g,
      (__attribute__((address_space(3))) unsigned int*)l, 16, 0, 0);
}

// One 64-lane DMA slice (j in 0..4) of a halo row (66 px x 32 ch, row-major 32ch/px).
__device__ __forceinline__ void stage_one(const short* __restrict__ rowPtr, bool rowOK,
                                          short* dstRow, int lane,
                                          const short* __restrict__ zp, int j) {
  int e = j * 64 + lane;
  int px = e >> 2, v = e & 3;
  int xx = px - 1;
  bool ok = rowOK && (px < 66) && (xx >= 0) && (xx < 64);
  const short* g = ok ? (rowPtr + (size_t)xx * CS + v * 8) : zp;
  async_ld16(g, dstRow + e * 8);
}

// Full 5-DMA stage (prologue only).
__device__ __forceinline__ void stage_row(const short* __restrict__ rowPtr, bool rowOK,
                                          short* dstRow, int lane,
                                          const short* __restrict__ zp) {
  #pragma unroll
  for (int j = 0; j < 5; ++j) stage_one(rowPtr, rowOK, dstRow, lane, zp, j);
}

// ---- dtype detect: fp32 low-halves have uniform bits[14:7]; bf16 weights cluster ----
__global__ void detect_dtype(const unsigned short* __restrict__ w0, int* __restrict__ flag) {
  int lane = threadIdx.x;
  int cnt = 0;
  for (int i = 0; i < 4; ++i) {
    unsigned short u = w0[2 * (lane + 64 * i)];
    int e = (u >> 7) & 0xFF;
    unsigned long long b = __ballot(e >= 0xC0);
    cnt += __popcll(b);
  }
  if (lane == 0) *flag = (cnt > 32) ? 1 : 0;   // 1 = fp32 inputs
}

__global__ void canon_b(const void* __restrict__ b0, const void* __restrict__ b1,
                        float* __restrict__ Bc0, float* __restrict__ Bc1,
                        const int* __restrict__ flag) {
  int i = blockIdx.x * 256 + threadIdx.x;
  int fl = *flag;
  if (i < 512) {
    float v = fl ? ((const float*)b0)[i] : bs2f(((const short*)b0)[i]);
    if (!isfinite(v) || fabsf(v) > 1e4f) v = 0.f;
    Bc0[i] = v;
  } else if (i < 560) {
    int j = i - 512;
    float v = fl ? ((const float*)b1)[j] : bs2f(((const short*)b1)[j]);
    if (!isfinite(v) || fabsf(v) > 1e4f) v = 0.f;
    Bc1[j] = v;
  }
}

__device__ __forceinline__ float ldw(const void* W, int idx, int fl) {
  float w = fl ? ((const float*)W)[idx] : bs2f(((const short*)W)[idx]);
  if (!isfinite(w) || fabsf(w) > 1e4f) w = 0.f;
  return w;
}

// layer0 h0 weights: Wp0[co][tap*128+c] = W0[co][1+c][tap]  (512 x 1152)
__global__ void prep_w0(const void* __restrict__ W0, short* __restrict__ Wp,
                        const int* __restrict__ flag) {
  int i = blockIdx.x * 256 + threadIdx.x;
  if (i >= 512 * KT0) return;
  int fl = *flag;
  int co = i / KT0, k = i - co * KT0;
  int tap = k >> 7, c = k & 127;
  Wp[i] = f2hs(ldw(W0, (co * 129 + 1 + c) * 9 + tap, fl));
}

// layer0 x weights: Wx[co][16], k<9 -> W0[co][0][k], else 0  (512 x 16)
__global__ void prep_wx(const void* __restrict__ W0, short* __restrict__ Wx,
                        const int* __restrict__ flag) {
  int i = blockIdx.x * 256 + threadIdx.x;
  if (i >= 512 * 16) return;
  int fl = *flag;
  int co = i >> 4, k = i & 15;
  float w = (k < 9) ? ldw(W0, (co * 129) * 9 + k, fl) : 0.f;
  Wx[i] = f2hs(w);
}

// layer1 weights: Wp1[co][tap*160+c]: c<140 -> W1[co][c][tap] (h0 at P-ch0..127,
// h1 at P-ch128..139), else 0.  (48 x 1440)
__global__ void prep_w1(const void* __restrict__ W1, short* __restrict__ Wp,
                        const int* __restrict__ flag) {
  int i = blockIdx.x * 256 + threadIdx.x;
  if (i >= 48 * KTOT) return;
  int fl = *flag;
  int co = i / KTOT, k = i - co * KTOT;
  int tap = k / CS, c = k - tap * CS;
  float w = (c < 140) ? ldw(W1, (co * 140 + c) * 9 + tap, fl) : 0.f;
  Wp[i] = f2hs(w);
}

// Xtap[t][p][16]: k<9 = sanitized x[t] at tap-shifted pixel (0 at borders), k>=9 = 0.
__global__ void prep_xtap(const void* __restrict__ hist, short* __restrict__ Xtap,
                          const int* __restrict__ flag) {
  int i = blockIdx.x * 256 + threadIdx.x;      // < 786432 = 12*65536
  int t = i >> 16, p = i & 65535;
  int b = p >> 12, pix = p & 4095, y = pix >> 6, x = pix & 63;
  int fl = *flag;
  short8 lo = {0, 0, 0, 0, 0, 0, 0, 0}, hi = {0, 0, 0, 0, 0, 0, 0, 0};
  #pragma unroll
  for (int k = 0; k < 9; ++k) {
    int dy = k / 3, dx = k - dy * 3;
    int yy = y + dy - 1, xx = x + dx - 1;
    float f = 0.f;
    if (yy >= 0 && yy < 64 && xx >= 0 && xx < 64) {
      int hidx = (b * 12 + t) * 4096 + yy * 64 + xx;
      f = fl ? ((const float*)hist)[hidx] : bs2f(((const short*)hist)[hidx]);
      if (!isfinite(f) || fabsf(f) > 1e4f) f = 0.f;
    }
    if (k < 8) lo[k] = f2hs(f); else hi[k - 8] = f2hs(f);
  }
  *(short8*)(Xtap + (size_t)i * 16) = lo;
  *(short8*)(Xtap + (size_t)i * 16 + 8) = hi;
}

// ---- layer 0: block = 256px (4 rows) x 256co (64 hc x 4 gates), 512 thr (8 waves).
// Grid = 2 nth * 256 mt = 512. Waves: wm = row pair, wcol = 16-ch group. ----
__global__ __launch_bounds__(512, 4) void gemm_gate0(
    const short* __restrict__ Pcur, short* __restrict__ Pnext,
    const short* __restrict__ Wp, const short* __restrict__ Wx,
    const float* __restrict__ Bc0, float* __restrict__ C0,
    const short* __restrict__ Xtap, const short* __restrict__ zp, int t) {
  // XCD stripe swizzle: XCD x owns mt in [32x,32x+32) (= 2 batches of P), both nth.
  int pbx = blockIdx.x;
  int xcd = pbx & 7, l = pbx >> 3;             // l 0..63
  int mt = xcd * 32 + (l & 31);                // 0..255
  int nth = l >> 5;                            // 0..1 (64-ch half)
  int b = mt >> 4, y0 = (mt & 15) * 4;
  int tid = threadIdx.x, wave = tid >> 6, lane = tid & 63;
  int ln15 = lane & 15, quad = lane >> 4;
  int wm = wave & 1, wcol = wave >> 1;         // wm: rows [wm*2,wm*2+1]; wcol: 0..3
  int hc = nth * 64 + wcol * 16 + ln15;

  __shared__ __align__(16) short halo[2 * BSTR6];   // dbuf, 61440 B

  float4v acc[8][4];
  #pragma unroll
  for (int i2 = 0; i2 < 8; ++i2)
    #pragma unroll
    for (int j = 0; j < 4; ++j) acc[i2][j] = (float4v){0.f, 0.f, 0.f, 0.f};

  // B frag addr (g, tap, c0): wbase + g*128*KT0 + tap*128 + c0
  const short* wbase = Wp + (size_t)hc * KT0 + quad * 8;
  short8 bcur[4], bnxt[4];
  #pragma unroll
  for (int g = 0; g < 4; ++g)
    bcur[g] = *(const short8*)(wbase + (size_t)g * 128 * KT0);

  // 6 halo rows (y0-1 .. y0+4): wave w (w<6) owns row w. Waves 6,7 compute-only.
  int yy = y0 - 1 + wave;
  bool rowOK = (yy >= 0) && (yy < 64);
  const short* rowBase = Pcur + (size_t)((b * 64 + yy) * 64) * CS;

  // x-phase operand loads FIRST: consuming them later only drains the vmcnt FIFO
  // up to here (no staging DMA is ahead of them).
  bool hiQ = quad >= 2;
  short8 ax[8], bxr[4];
  #pragma unroll
  for (int mf = 0; mf < 8; ++mf) {
    int row = y0 + wm * 2 + (mf >> 2);
    int pixB = (b * 64 + row) * 64 + (mf & 3) * 16 + ln15;
    ax[mf] = *(const short8*)(Xtap + ((size_t)t * 65536 + pixB) * 16 + (quad & 1) * 8);
  }
  #pragma unroll
  for (int g = 0; g < 4; ++g) {
    const short* wxp = Wx + (size_t)(g * 128 + hc) * 16 + (quad & 1) * 8;
    bxr[g] = *(const short8*)(hiQ ? zp : wxp);
  }

  if (wave < 6) stage_row(rowBase, rowOK, halo + wave * RSTR, lane, zp);

  // tap-packed x phase: K=32 MFMA, k=taps (0..8 live); B zeros for k>=16 kill the
  // garbage A upper half. Runs while staging DMAs are in flight.
  #pragma unroll
  for (int g = 0; g < 4; ++g)
    #pragma unroll
    for (int mf = 0; mf < 8; ++mf)
      acc[mf][g] = __builtin_amdgcn_mfma_f32_16x16x32_f16(ax[mf], bxr[g], acc[mf][g], 0, 0, 0);
  __syncthreads();

  for (int ch = 0; ch < 4; ++ch) {
    int c0 = ch * 32;
    const short* cur = halo + (ch & 1) * BSTR6;
    short* nd = halo + ((ch + 1) & 1) * BSTR6;
    const short* src = rowBase + c0 + 32;
    #pragma unroll
    for (int tap = 0; tap < 9; ++tap) {
      int dy = tap / 3, dx = tap - dy * 3;
      // spread staging (R19): <=1 DMA slice per wave per tap, taps 0..4
      if (ch < 3 && tap < 5 && wave < 6)
        stage_one(src, rowOK, nd + wave * RSTR, lane, zp, tap);
      // prefetch next tap's (or next chunk's tap-0) B fragments
      int ntap = (tap < 8) ? tap + 1 : 0;
      int nc0 = (tap < 8) ? c0 : ((ch < 3) ? c0 + 32 : c0);
      #pragma unroll
      for (int g = 0; g < 4; ++g)
        bnxt[g] = *(const short8*)(wbase + (size_t)g * 128 * KT0 + ntap * 128 + nc0);

      short8 af[8];
      #pragma unroll
      for (int mf = 0; mf < 8; ++mf)
        af[mf] = *(const short8*)&cur[(wm * 2 + (mf >> 2) + dy) * RSTR
                                      + ((mf & 3) * 16 + ln15 + dx) * 32 + quad * 8];
      #pragma unroll
      for (int g = 0; g < 4; ++g)
        #pragma unroll
        for (int mf = 0; mf < 8; ++mf)
          acc[mf][g] = __builtin_amdgcn_mfma_f32_16x16x32_f16(af[mf], bcur[g], acc[mf][g], 0, 0, 0);
      #pragma unroll
      for (int g = 0; g < 4; ++g) bcur[g] = bnxt[g];
    }
    __syncthreads();
  }

  // epilogue: all 4 gates in-register per (pix,hc); 8 mf = 2 rows x 4 x-frags.
  // h0 write at ch0..127: bytes [0,256) of the 320B pixel -- sector-aligned.
  float bi = Bc0[hc], bff = Bc0[128 + hc], bo = Bc0[256 + hc], bg = Bc0[384 + hc];
  #pragma unroll
  for (int mf = 0; mf < 8; ++mf) {
    int row = y0 + wm * 2 + (mf >> 2);
    int pixRow = (b * 64 + row) * 64;
    #pragma unroll
    for (int r = 0; r < 4; ++r) {
      int x = (mf & 3) * 16 + quad * 4 + r;    // C/D row = quad*4 + reg
      int pix = pixRow + x;
      float zi = acc[mf][0][r] + bi;
      float zf = acc[mf][1][r] + bff;
      float zo = acc[mf][2][r] + bo;
      float zg = acc[mf][3][r] + bg;
      float cprev = C0[(size_t)pix * 128 + hc];
      float cn = sigf(zf) * cprev + sigf(zi) * tanhf(zg);
      float hn = sigf(zo) * tanhf(cn);
      C0[(size_t)pix * 128 + hc] = cn;
      Pnext[(size_t)pix * CS + hc] = f2hs(hn);
    }
  }
}

// ---- layer 1: M=128px (2 rows) x N=48co. Grid 512. B register-prefetch. ----
__global__ __launch_bounds__(256, 2) void gemm_gate1(
    const short* __restrict__ Prd, short* __restrict__ Pwr,
    const short* __restrict__ Wp, const float* __restrict__ Bc1,
    float* __restrict__ C1, void* __restrict__ outp,
    const short* __restrict__ zp, const int* __restrict__ flagp, int t) {
  // XCD stripe swizzle: XCD x owns bid in [64x, 64x+64) = 2 batches (L2-fit halos).
  int pbx = blockIdx.x;
  int bid = (pbx & 7) * 64 + (pbx >> 3);
  int b = bid >> 5, y0 = (bid & 31) * 2;
  int tid = threadIdx.x, wave = tid >> 6, lane = tid & 63;
  int ln15 = lane & 15, quad = lane >> 4;
  int wr = wave >> 1, wh = wave & 1;
  int flagv = *flagp;

  __shared__ __align__(16) short halo[2 * BSTR];   // 40960 B

  float4v acc[2][3];
  #pragma unroll
  for (int i = 0; i < 2; ++i)
    #pragma unroll
    for (int j = 0; j < 3; ++j) acc[i][j] = (float4v){0.f, 0.f, 0.f, 0.f};

  int yy = y0 - 1 + wave;
  bool rowOK = (yy >= 0) && (yy < 64);
  const short* rowBase = Prd + (size_t)((b * 64 + yy) * 64) * CS;

  const short* wbase = Wp + (size_t)ln15 * KTOT + quad * 8;
  short8 bcur[3], bnxt[3];
  #pragma unroll
  for (int nf = 0; nf < 3; ++nf)
    bcur[nf] = *(const short8*)(wbase + (size_t)nf * 16 * KTOT);

  stage_row(rowBase, rowOK, halo + wave * RSTR, lane, zp);
  __syncthreads();

  for (int ch = 0; ch < 5; ++ch) {
    int c0 = ch * 32;
    const short* cur = halo + (ch & 1) * BSTR;
    short* nxtDst = halo + ((ch + 1) & 1) * BSTR + wave * RSTR;
    const short* nxtSrc = rowBase + c0 + 32;
    #pragma unroll
    for (int tap = 0; tap < 9; ++tap) {
      int dy = tap / 3, dx = tap - dy * 3;
      if (ch < 4 && tap < 5)
        stage_one(nxtSrc, rowOK, nxtDst, lane, zp, tap);
      int ntap = (tap < 8) ? tap + 1 : 0;
      int nc0 = (tap < 8) ? c0 : ((ch < 4) ? c0 + 32 : c0);
      #pragma unroll
      for (int nf = 0; nf < 3; ++nf)
        bnxt[nf] = *(const short8*)(wbase + (size_t)nf * 16 * KTOT + ntap * CS + nc0);

      short8 af[2];
      #pragma unroll
      for (int mf = 0; mf < 2; ++mf)
        af[mf] = *(const short8*)&cur[(wr + dy) * RSTR + (wh * 32 + mf * 16 + ln15 + dx) * 32
                                      + quad * 8];
      #pragma unroll
      for (int nf = 0; nf < 3; ++nf)
        #pragma unroll
        for (int mf = 0; mf < 2; ++mf)
          acc[mf][nf] = __builtin_amdgcn_mfma_f32_16x16x32_f16(af[mf], bcur[nf], acc[mf][nf], 0, 0, 0);
      #pragma unroll
      for (int nf = 0; nf < 3; ++nf) bcur[nf] = bnxt[nf];
    }
    __syncthreads();
  }

  // z -> LDS (reuse halo: 128*48 fp32 = 24576 B), then gate pass
  float* zbuf = (float*)halo;
  #pragma unroll
  for (int mf = 0; mf < 2; ++mf)
    #pragma unroll
    for (int nf = 0; nf < 3; ++nf)
      #pragma unroll
      for (int r = 0; r < 4; ++r) {
        int pxl = wr * 64 + wh * 32 + mf * 16 + quad * 4 + r;
        zbuf[pxl * 48 + nf * 16 + ln15] = acc[mf][nf][r];
      }
  __syncthreads();

  #pragma unroll
  for (int k = 0; k < 6; ++k) {
    int id = k * 256 + tid;
    int hc = id >> 7, pxl = id & 127;
    float zi = zbuf[pxl * 48 + hc]      + Bc1[hc];
    float zf = zbuf[pxl * 48 + 12 + hc] + Bc1[12 + hc];
    float zo = zbuf[pxl * 48 + 24 + hc] + Bc1[24 + hc];
    float zg = zbuf[pxl * 48 + 36 + hc] + Bc1[36 + hc];
    int y = y0 + (pxl >> 6), x = pxl & 63;
    int pix = (b * 64 + y) * 64 + x;
    float cprev = C1[(size_t)pix * 12 + hc];
    float cn = sigf(zf) * cprev + sigf(zi) * tanhf(zg);
    float hn = sigf(zo) * tanhf(cn);
    C1[(size_t)pix * 12 + hc] = cn;
    Pwr[(size_t)pix * CS + 128 + hc] = f2hs(hn);   // h1 at ch128..139
    if (t == 11) {
      int oidx = (b * 12 + hc) * 4096 + y * 64 + x;
      if (flagv) ((float*)outp)[oidx] = hn;
      else ((short*)outp)[oidx] = f2bs(hn);
    }
  }
}

extern "C" void kernel_launch(void* const* d_in, const int* in_sizes, int n_in,
                              void* d_out, int out_size, void* d_ws, size_t ws_size,
                              hipStream_t stream) {
  const void* hist = d_in[0];                  // (16,12,4096,1)
  const void* W0 = d_in[2];                    // (512,129,3,3)
  const void* b0 = d_in[3];
  const void* W1 = d_in[4];                    // (48,140,3,3)
  const void* b1 = d_in[5];

  char* ws = (char*)d_ws;
  const size_t PszB = (size_t)16 * 4096 * CS * 2;     // 20,971,520
  short* P[2] = {(short*)ws, (short*)(ws + PszB)};
  float* C0 = (float*)(ws + 2 * PszB);                // 33,554,432
  const size_t C0e = 2 * PszB + 33554432;
  float* C1 = (float*)(ws + C0e);                     // 3,145,728
  const size_t C1e = C0e + 3145728;
  short* zp = (short*)(ws + C1e);                     // 256 B zero page
  const size_t zpe = C1e + 256;                       // memset to here
  short* Xtap = (short*)(ws + zpe);                   // 12*65536*16*2 = 25,165,824
  const size_t Xte = zpe + (size_t)12 * 65536 * 16 * 2;
  short* Wp0 = (short*)(ws + Xte);                    // 512*1152*2 = 1,179,648
  const size_t W0e = Xte + (size_t)512 * KT0 * 2;
  short* Wx0 = (short*)(ws + W0e);                    // 512*16*2 = 16,384
  const size_t Wxe = W0e + 512 * 16 * 2;
  short* Wp1 = (short*)(ws + Wxe);                    // 48*1440*2 = 138,240
  const size_t W1e = Wxe + (size_t)48 * KTOT * 2;
  float* Bc0 = (float*)(ws + W1e);                    // 2048
  float* Bc1 = (float*)(ws + W1e + 2048);             // 192
  int* flag = (int*)(ws + W1e + 2048 + 192);          // total ~105 MiB

  hipMemsetAsync(ws, 0, zpe, stream);                 // P pair + C0 + C1 + zero page
  detect_dtype<<<1, 64, 0, stream>>>((const unsigned short*)W0, flag);
  canon_b<<<3, 256, 0, stream>>>(b0, b1, Bc0, Bc1, flag);
  prep_w0<<<(512 * KT0 + 255) / 256, 256, 0, stream>>>(W0, Wp0, flag);
  prep_wx<<<32, 256, 0, stream>>>(W0, Wx0, flag);
  prep_w1<<<(48 * KTOT + 255) / 256, 256, 0, stream>>>(W1, Wp1, flag);
  prep_xtap<<<3072, 256, 0, stream>>>(hist, Xtap, flag);

  for (int t = 0; t < 12; ++t) {
    gemm_gate0<<<512, 512, 0, stream>>>(P[t & 1], P[(t + 1) & 1], Wp0, Wx0, Bc0, C0,
                                        Xtap, zp, t);
    gemm_gate1<<<512, 256, 0, stream>>>(P[(t + 1) & 1], P[t & 1], Wp1, Bc1, C1,
                                        d_out, zp, flag, t);
  }
}

// Round 12
// 7554.357 us; speedup vs baseline: 1.5128x; 1.5128x over previous
//
#include <hip/hip_runtime.h>
#include <hip/hip_bf16.h>

// ConvLSTM (2 layers) on MI355X. R23 = R21 (best, 1933us) + LDS shrink for 3 blocks/CU.
// R22 post-mortem: bounds(512,4) capped VGPR at 128 -> acc spilled to scratch (VGPR=64,
// 4.6GB/dispatch). Reverted to R21 geometry. R21's occupancy is LDS-capped (61440B ->
// 2 blocks/CU, 21%); rows were padded 2112->2560 shorts for tail-less 5-DMA staging.
// R23: exact-size rows (RSTR=2112). Staging = 4 full DMA slices (px 0..63) + 2-px
// register tail (slot64=x63, slot65=0), T14-split: tail load issued BEFORE the chunk's
// DMAs (its vmcnt wait drains nothing of this chunk), ds_write after tap 8. R15 proved
// register tails are neutral. LDS: gate0 50688B -> 3 blocks/CU (12 waves, 3/SIMD,
// +50% TLP), gate1 33792B -> 4 blocks/CU. bounds(256,3)/(256,4): caps 170/128 >= 
// measured 128/52, no spill. All else identical to R21 (dead-K removal, Xtap x-phase,
// 4-row M-tile acc 8x4, R19 spread staging, XCD stripe swizzle, zero page, tanhf).

typedef __attribute__((ext_vector_type(8))) short short8;
typedef __attribute__((ext_vector_type(4))) float float4v;

#define CS 160
#define KT0 1152          // gate0 K = 9*128 (pure h0)
#define KTOT 1440         // gate1 K = 9*160
#define RSTR 2112         // LDS halo row stride (shorts) = 66 px * 32 ch, exact
#define BSTR4 8448        // gate1 LDS buffer stride (shorts) = 4 * RSTR
#define BSTR6 12672       // gate0 LDS buffer stride (shorts) = 6 * RSTR

__device__ __forceinline__ float sigf(float x) { return 1.f / (1.f + __expf(-x)); }
__device__ __forceinline__ short f2hs(float v) {
  _Float16 h = (_Float16)v;
  return *(short*)&h;
}
__device__ __forceinline__ float bs2f(short s) {
  __hip_bfloat16 h; *(short*)&h = s; return __bfloat162float(h);
}
__device__ __forceinline__ short f2bs(float v) {
  __hip_bfloat16 h = __float2bfloat16(v);
  return *(short*)&h;
}

// async 16B global->LDS; per-lane lds ptr must equal uniform_base + lane*16
__device__ __forceinline__ void async_ld16(const short* g, short* l) {
  __builtin_amdgcn_global_load_lds(
      (const __attribute__((address_space(1))) unsigned int*)g,
      (__attribute__((address_space(3))) unsigned int*)l, 16, 0, 0);
}

// One 64-lane DMA slice (j in 0..3) covering LDS slots px = j*16 .. j*16+15
// (all interior: xx = px-1 in [-1,62]; xx=-1 reads zero page).
__device__ __forceinline__ void stage_one4(const short* __restrict__ rowPtr, bool rowOK,
                                           short* dstRow, int lane,
                                           const short* __restrict__ zp, int j) {
  int e = j * 64 + lane;
  int px = e >> 2, v = e & 3;
  int xx = px - 1;
  bool ok = rowOK && (xx >= 0);
  const short* g = ok ? (rowPtr + (size_t)xx * CS + v * 8) : zp;
  async_ld16(g, dstRow + e * 8);
}

// Full 4-slice interior stage (prologue helper).
__device__ __forceinline__ void stage_row4(const short* __restrict__ rowPtr, bool rowOK,
                                           short* dstRow, int lane,
                                           const short* __restrict__ zp) {
  #pragma unroll
  for (int j = 0; j < 4; ++j) stage_one4(rowPtr, rowOK, dstRow, lane, zp, j);
}

// Tail load (call BEFORE issuing the chunk's DMA slices): lanes 0..3 load slot64
// (= global x 63) ch-group lane; others zero. Slot 65 is always zero.
__device__ __forceinline__ short8 tail_load(const short* __restrict__ srcChunk,
                                            bool rowOK, int lane) {
  short8 tv = {0, 0, 0, 0, 0, 0, 0, 0};
  if (lane < 4 && rowOK) tv = *(const short8*)(srcChunk + (size_t)63 * CS + lane * 8);
  return tv;
}

// Tail write (call after last consumption of the previous buffer, before barrier).
__device__ __forceinline__ void tail_write(short* dstRow, int lane, short8 tv) {
  if (lane < 8) {
    short8 w = {0, 0, 0, 0, 0, 0, 0, 0};
    if (lane < 4) w = tv;
    *(short8*)(dstRow + (64 + (lane >> 2)) * 32 + (lane & 3) * 8) = w;
  }
}

// ---- dtype detect: fp32 low-halves have uniform bits[14:7]; bf16 weights cluster ----
__global__ void detect_dtype(const unsigned short* __restrict__ w0, int* __restrict__ flag) {
  int lane = threadIdx.x;
  int cnt = 0;
  for (int i = 0; i < 4; ++i) {
    unsigned short u = w0[2 * (lane + 64 * i)];
    int e = (u >> 7) & 0xFF;
    unsigned long long b = __ballot(e >= 0xC0);
    cnt += __popcll(b);
  }
  if (lane == 0) *flag = (cnt > 32) ? 1 : 0;   // 1 = fp32 inputs
}

__global__ void canon_b(const void* __restrict__ b0, const void* __restrict__ b1,
                        float* __restrict__ Bc0, float* __restrict__ Bc1,
                        const int* __restrict__ flag) {
  int i = blockIdx.x * 256 + threadIdx.x;
  int fl = *flag;
  if (i < 512) {
    float v = fl ? ((const float*)b0)[i] : bs2f(((const short*)b0)[i]);
    if (!isfinite(v) || fabsf(v) > 1e4f) v = 0.f;
    Bc0[i] = v;
  } else if (i < 560) {
    int j = i - 512;
    float v = fl ? ((const float*)b1)[j] : bs2f(((const short*)b1)[j]);
    if (!isfinite(v) || fabsf(v) > 1e4f) v = 0.f;
    Bc1[j] = v;
  }
}

__device__ __forceinline__ float ldw(const void* W, int idx, int fl) {
  float w = fl ? ((const float*)W)[idx] : bs2f(((const short*)W)[idx]);
  if (!isfinite(w) || fabsf(w) > 1e4f) w = 0.f;
  return w;
}

// layer0 h0 weights: Wp0[co][tap*128+c] = W0[co][1+c][tap]  (512 x 1152)
__global__ void prep_w0(const void* __restrict__ W0, short* __restrict__ Wp,
                        const int* __restrict__ flag) {
  int i = blockIdx.x * 256 + threadIdx.x;
  if (i >= 512 * KT0) return;
  int fl = *flag;
  int co = i / KT0, k = i - co * KT0;
  int tap = k >> 7, c = k & 127;
  Wp[i] = f2hs(ldw(W0, (co * 129 + 1 + c) * 9 + tap, fl));
}

// layer0 x weights: Wx[co][16], k<9 -> W0[co][0][k], else 0  (512 x 16)
__global__ void prep_wx(const void* __restrict__ W0, short* __restrict__ Wx,
                        const int* __restrict__ flag) {
  int i = blockIdx.x * 256 + threadIdx.x;
  if (i >= 512 * 16) return;
  int fl = *flag;
  int co = i >> 4, k = i & 15;
  float w = (k < 9) ? ldw(W0, (co * 129) * 9 + k, fl) : 0.f;
  Wx[i] = f2hs(w);
}

// layer1 weights: Wp1[co][tap*160+c]: c<140 -> W1[co][c][tap] (h0 at P-ch0..127,
// h1 at P-ch128..139), else 0.  (48 x 1440)
__global__ void prep_w1(const void* __restrict__ W1, short* __restrict__ Wp,
                        const int* __restrict__ flag) {
  int i = blockIdx.x * 256 + threadIdx.x;
  if (i >= 48 * KTOT) return;
  int fl = *flag;
  int co = i / KTOT, k = i - co * KTOT;
  int tap = k / CS, c = k - tap * CS;
  float w = (c < 140) ? ldw(W1, (co * 140 + c) * 9 + tap, fl) : 0.f;
  Wp[i] = f2hs(w);
}

// Xtap[t][p][16]: k<9 = sanitized x[t] at tap-shifted pixel (0 at borders), k>=9 = 0.
__global__ void prep_xtap(const void* __restrict__ hist, short* __restrict__ Xtap,
                          const int* __restrict__ flag) {
  int i = blockIdx.x * 256 + threadIdx.x;      // < 786432 = 12*65536
  int t = i >> 16, p = i & 65535;
  int b = p >> 12, pix = p & 4095, y = pix >> 6, x = pix & 63;
  int fl = *flag;
  short8 lo = {0, 0, 0, 0, 0, 0, 0, 0}, hi = {0, 0, 0, 0, 0, 0, 0, 0};
  #pragma unroll
  for (int k = 0; k < 9; ++k) {
    int dy = k / 3, dx = k - dy * 3;
    int yy = y + dy - 1, xx = x + dx - 1;
    float f = 0.f;
    if (yy >= 0 && yy < 64 && xx >= 0 && xx < 64) {
      int hidx = (b * 12 + t) * 4096 + yy * 64 + xx;
      f = fl ? ((const float*)hist)[hidx] : bs2f(((const short*)hist)[hidx]);
      if (!isfinite(f) || fabsf(f) > 1e4f) f = 0.f;
    }
    if (k < 8) lo[k] = f2hs(f); else hi[k - 8] = f2hs(f);
  }
  *(short8*)(Xtap + (size_t)i * 16) = lo;
  *(short8*)(Xtap + (size_t)i * 16 + 8) = hi;
}

// ---- layer 0: M=256px (4 rows) x N=128co. Grid = 4 nt * 256 mt = 1024. ----
__global__ __launch_bounds__(256, 3) void gemm_gate0(
    const short* __restrict__ Pcur, short* __restrict__ Pnext,
    const short* __restrict__ Wp, const short* __restrict__ Wx,
    const float* __restrict__ Bc0, float* __restrict__ C0,
    const short* __restrict__ Xtap, const short* __restrict__ zp, int t) {
  // XCD stripe swizzle: XCD x owns mt in [32x,32x+32) (= 2 batches of P) for ALL nt.
  int pbx = blockIdx.x;
  int xcd = pbx & 7, i = pbx >> 3;             // i 0..127
  int mt = xcd * 32 + (i & 31);                // 0..255
  int nt = i >> 5;                             // 0..3
  int b = mt >> 4, y0 = (mt & 15) * 4;
  int tid = threadIdx.x, wave = tid >> 6, lane = tid & 63;
  int ln15 = lane & 15, quad = lane >> 4;
  int wm = wave & 1, wn = wave >> 1;           // wave tile: rows [wm*2, wm*2+1], co half wn
  int hc = nt * 32 + wn * 16 + ln15;

  __shared__ __align__(16) short halo[2 * BSTR6];   // dbuf, 50688 B -> 3 blocks/CU

  float4v acc[8][4];
  #pragma unroll
  for (int i2 = 0; i2 < 8; ++i2)
    #pragma unroll
    for (int j = 0; j < 4; ++j) acc[i2][j] = (float4v){0.f, 0.f, 0.f, 0.f};

  // B frag addr (g, tap, c0): wbase + g*128*KT0 + tap*128 + c0
  const short* wbase = Wp + (size_t)hc * KT0 + quad * 8;
  short8 bcur[4], bnxt[4];
  #pragma unroll
  for (int g = 0; g < 4; ++g)
    bcur[g] = *(const short8*)(wbase + (size_t)g * 128 * KT0);

  // 6 halo rows (y0-1 .. y0+4): wave w stages LDS row w; waves 0,1 also rows 4,5.
  int yyA = y0 - 1 + wave;
  bool okA = (yyA >= 0) && (yyA < 64);
  const short* baseA = Pcur + (size_t)((b * 64 + yyA) * 64) * CS;
  int yyB = y0 + 3 + wave;                     // rows 4,5 (waves 0,1 only)
  bool okB = (wave < 2) && (yyB < 64);
  const short* baseB = Pcur + (size_t)((b * 64 + yyB) * 64) * CS;

  // x-phase operand loads + prologue tail loads FIRST (before any DMA in the FIFO).
  bool hiQ = quad >= 2;
  short8 ax[8], bxr[4];
  #pragma unroll
  for (int mf = 0; mf < 8; ++mf) {
    int row = y0 + wm * 2 + (mf >> 2);
    int pixB = (b * 64 + row) * 64 + (mf & 3) * 16 + ln15;
    ax[mf] = *(const short8*)(Xtap + ((size_t)t * 65536 + pixB) * 16 + (quad & 1) * 8);
  }
  #pragma unroll
  for (int g = 0; g < 4; ++g) {
    const short* wxp = Wx + (size_t)(g * 128 + hc) * 16 + (quad & 1) * 8;
    bxr[g] = *(const short8*)(hiQ ? zp : wxp);
  }
  short8 tA = tail_load(baseA, okA, lane);
  short8 tB = tail_load(baseB, okB, lane);

  stage_row4(baseA, okA, halo + wave * RSTR, lane, zp);
  if (wave < 2) stage_row4(baseB, okB, halo + (4 + wave) * RSTR, lane, zp);

  // tap-packed x phase: K=32 MFMA, k=taps (0..8 live); runs while DMAs fly.
  #pragma unroll
  for (int g = 0; g < 4; ++g)
    #pragma unroll
    for (int mf = 0; mf < 8; ++mf)
      acc[mf][g] = __builtin_amdgcn_mfma_f32_16x16x32_f16(ax[mf], bxr[g], acc[mf][g], 0, 0, 0);

  tail_write(halo + wave * RSTR, lane, tA);
  if (wave < 2) tail_write(halo + (4 + wave) * RSTR, lane, tB);
  __syncthreads();

  for (int ch = 0; ch < 4; ++ch) {
    int c0 = ch * 32;
    const short* cur = halo + (ch & 1) * BSTR6;
    short* nd = halo + ((ch + 1) & 1) * BSTR6;
    const short* srcA = baseA + c0 + 32;
    const short* srcB = baseB + c0 + 32;
    // tail loads for next chunk issued BEFORE this chunk's DMA slices (T14 split):
    // their vmcnt wait at tail_write drains nothing staged this chunk.
    short8 nA = {0, 0, 0, 0, 0, 0, 0, 0}, nB = {0, 0, 0, 0, 0, 0, 0, 0};
    if (ch < 3) {
      nA = tail_load(srcA, okA, lane);
      if (wave < 2) nB = tail_load(srcB, okB, lane);
    }
    #pragma unroll
    for (int tap = 0; tap < 9; ++tap) {
      int dy = tap / 3, dx = tap - dy * 3;
      // spread staging (R19): one DMA slice per tap, taps 0..3
      if (ch < 3 && tap < 4) {
        stage_one4(srcA, okA, nd + wave * RSTR, lane, zp, tap);
        if (wave < 2) stage_one4(srcB, okB, nd + (4 + wave) * RSTR, lane, zp, tap);
      }
      // prefetch next tap's (or next chunk's tap-0) B fragments
      int ntap = (tap < 8) ? tap + 1 : 0;
      int nc0 = (tap < 8) ? c0 : ((ch < 3) ? c0 + 32 : c0);
      #pragma unroll
      for (int g = 0; g < 4; ++g)
        bnxt[g] = *(const short8*)(wbase + (size_t)g * 128 * KT0 + ntap * 128 + nc0);

      short8 af[8];
      #pragma unroll
      for (int mf = 0; mf < 8; ++mf)
        af[mf] = *(const short8*)&cur[(wm * 2 + (mf >> 2) + dy) * RSTR
                                      + ((mf & 3) * 16 + ln15 + dx) * 32 + quad * 8];
      #pragma unroll
      for (int g = 0; g < 4; ++g)
        #pragma unroll
        for (int mf = 0; mf < 8; ++mf)
          acc[mf][g] = __builtin_amdgcn_mfma_f32_16x16x32_f16(af[mf], bcur[g], acc[mf][g], 0, 0, 0);
      #pragma unroll
      for (int g = 0; g < 4; ++g) bcur[g] = bnxt[g];
    }
    if (ch < 3) {
      tail_write(nd + wave * RSTR, lane, nA);
      if (wave < 2) tail_write(nd + (4 + wave) * RSTR, lane, nB);
    }
    __syncthreads();
  }

  // epilogue: all 4 gates in-register per (pix,hc); 8 mf = 2 rows x 4 x-frags.
  float bi = Bc0[hc], bff = Bc0[128 + hc], bo = Bc0[256 + hc], bg = Bc0[384 + hc];
  #pragma unroll
  for (int mf = 0; mf < 8; ++mf) {
    int row = y0 + wm * 2 + (mf >> 2);
    int pixRow = (b * 64 + row) * 64;
    #pragma unroll
    for (int r = 0; r < 4; ++r) {
      int x = (mf & 3) * 16 + quad * 4 + r;    // C/D row = quad*4 + reg
      int pix = pixRow + x;
      float zi = acc[mf][0][r] + bi;
      float zf = acc[mf][1][r] + bff;
      float zo = acc[mf][2][r] + bo;
      float zg = acc[mf][3][r] + bg;
      float cprev = C0[(size_t)pix * 128 + hc];
      float cn = sigf(zf) * cprev + sigf(zi) * tanhf(zg);
      float hn = sigf(zo) * tanhf(cn);
      C0[(size_t)pix * 128 + hc] = cn;
      Pnext[(size_t)pix * CS + hc] = f2hs(hn);
    }
  }
}

// ---- layer 1: M=128px (2 rows) x N=48co. Grid 512. B register-prefetch. ----
__global__ __launch_bounds__(256, 4) void gemm_gate1(
    const short* __restrict__ Prd, short* __restrict__ Pwr,
    const short* __restrict__ Wp, const float* __restrict__ Bc1,
    float* __restrict__ C1, void* __restrict__ outp,
    const short* __restrict__ zp, const int* __restrict__ flagp, int t) {
  // XCD stripe swizzle: XCD x owns bid in [64x, 64x+64) = 2 batches (L2-fit halos).
  int pbx = blockIdx.x;
  int bid = (pbx & 7) * 64 + (pbx >> 3);
  int b = bid >> 5, y0 = (bid & 31) * 2;
  int tid = threadIdx.x, wave = tid >> 6, lane = tid & 63;
  int ln15 = lane & 15, quad = lane >> 4;
  int wr = wave >> 1, wh = wave & 1;
  int flagv = *flagp;

  __shared__ __align__(16) short halo[2 * BSTR4];   // 33792 B -> 4 blocks/CU

  float4v acc[2][3];
  #pragma unroll
  for (int i = 0; i < 2; ++i)
    #pragma unroll
    for (int j = 0; j < 3; ++j) acc[i][j] = (float4v){0.f, 0.f, 0.f, 0.f};

  int yy = y0 - 1 + wave;
  bool rowOK = (yy >= 0) && (yy < 64);
  const short* rowBase = Prd + (size_t)((b * 64 + yy) * 64) * CS;

  const short* wbase = Wp + (size_t)ln15 * KTOT + quad * 8;
  short8 bcur[3], bnxt[3];
  #pragma unroll
  for (int nf = 0; nf < 3; ++nf)
    bcur[nf] = *(const short8*)(wbase + (size_t)nf * 16 * KTOT);

  short8 tP = tail_load(rowBase, rowOK, lane);
  stage_row4(rowBase, rowOK, halo + wave * RSTR, lane, zp);
  tail_write(halo + wave * RSTR, lane, tP);
  __syncthreads();

  for (int ch = 0; ch < 5; ++ch) {
    int c0 = ch * 32;
    const short* cur = halo + (ch & 1) * BSTR4;
    short* nxtDst = halo + ((ch + 1) & 1) * BSTR4 + wave * RSTR;
    const short* nxtSrc = rowBase + c0 + 32;
    short8 nP = {0, 0, 0, 0, 0, 0, 0, 0};
    if (ch < 4) nP = tail_load(nxtSrc, rowOK, lane);
    #pragma unroll
    for (int tap = 0; tap < 9; ++tap) {
      int dy = tap / 3, dx = tap - dy * 3;
      if (ch < 4 && tap < 4)
        stage_one4(nxtSrc, rowOK, nxtDst, lane, zp, tap);
      int ntap = (tap < 8) ? tap + 1 : 0;
      int nc0 = (tap < 8) ? c0 : ((ch < 4) ? c0 + 32 : c0);
      #pragma unroll
      for (int nf = 0; nf < 3; ++nf)
        bnxt[nf] = *(const short8*)(wbase + (size_t)nf * 16 * KTOT + ntap * CS + nc0);

      short8 af[2];
      #pragma unroll
      for (int mf = 0; mf < 2; ++mf)
        af[mf] = *(const short8*)&cur[(wr + dy) * RSTR + (wh * 32 + mf * 16 + ln15 + dx) * 32
                                      + quad * 8];
      #pragma unroll
      for (int nf = 0; nf < 3; ++nf)
        #pragma unroll
        for (int mf = 0; mf < 2; ++mf)
          acc[mf][nf] = __builtin_amdgcn_mfma_f32_16x16x32_f16(af[mf], bcur[nf], acc[mf][nf], 0, 0, 0);
      #pragma unroll
      for (int nf = 0; nf < 3; ++nf) bcur[nf] = bnxt[nf];
    }
    if (ch < 4) tail_write(nxtDst, lane, nP);
    __syncthreads();
  }

  // z -> LDS (reuse halo: 128*48 fp32 = 24576 B <= 33792), then gate pass
  float* zbuf = (float*)halo;
  #pragma unroll
  for (int mf = 0; mf < 2; ++mf)
    #pragma unroll
    for (int nf = 0; nf < 3; ++nf)
      #pragma unroll
      for (int r = 0; r < 4; ++r) {
        int pxl = wr * 64 + wh * 32 + mf * 16 + quad * 4 + r;
        zbuf[pxl * 48 + nf * 16 + ln15] = acc[mf][nf][r];
      }
  __syncthreads();

  #pragma unroll
  for (int k = 0; k < 6; ++k) {
    int id = k * 256 + tid;
    int hc = id >> 7, pxl = id & 127;
    float zi = zbuf[pxl * 48 + hc]      + Bc1[hc];
    float zf = zbuf[pxl * 48 + 12 + hc] + Bc1[12 + hc];
    float zo = zbuf[pxl * 48 + 24 + hc] + Bc1[24 + hc];
    float zg = zbuf[pxl * 48 + 36 + hc] + Bc1[36 + hc];
    int y = y0 + (pxl >> 6), x = pxl & 63;
    int pix = (b * 64 + y) * 64 + x;
    float cprev = C1[(size_t)pix * 12 + hc];
    float cn = sigf(zf) * cprev + sigf(zi) * tanhf(zg);
    float hn = sigf(zo) * tanhf(cn);
    C1[(size_t)pix * 12 + hc] = cn;
    Pwr[(size_t)pix * CS + 128 + hc] = f2hs(hn);   // h1 at ch128..139
    if (t == 11) {
      int oidx = (b * 12 + hc) * 4096 + y * 64 + x;
      if (flagv) ((float*)outp)[oidx] = hn;
      else ((short*)outp)[oidx] = f2bs(hn);
    }
  }
}

extern "C" void kernel_launch(void* const* d_in, const int* in_sizes, int n_in,
                              void* d_out, int out_size, void* d_ws, size_t ws_size,
                              hipStream_t stream) {
  const void* hist = d_in[0];                  // (16,12,4096,1)
  const void* W0 = d_in[2];                    // (512,129,3,3)
  const void* b0 = d_in[3];
  const void* W1 = d_in[4];                    // (48,140,3,3)
  const void* b1 = d_in[5];

  char* ws = (char*)d_ws;
  const size_t PszB = (size_t)16 * 4096 * CS * 2;     // 20,971,520
  short* P[2] = {(short*)ws, (short*)(ws + PszB)};
  float* C0 = (float*)(ws + 2 * PszB);                // 33,554,432
  const size_t C0e = 2 * PszB + 33554432;
  float* C1 = (float*)(ws + C0e);                     // 3,145,728
  const size_t C1e = C0e + 3145728;
  short* zp = (short*)(ws + C1e);                     // 256 B zero page
  const size_t zpe = C1e + 256;                       // memset to here
  short* Xtap = (short*)(ws + zpe);                   // 12*65536*16*2 = 25,165,824
  const size_t Xte = zpe + (size_t)12 * 65536 * 16 * 2;
  short* Wp0 = (short*)(ws + Xte);                    // 512*1152*2 = 1,179,648
  const size_t W0e = Xte + (size_t)512 * KT0 * 2;
  short* Wx0 = (short*)(ws + W0e);                    // 512*16*2 = 16,384
  const size_t Wxe = W0e + 512 * 16 * 2;
  short* Wp1 = (short*)(ws + Wxe);                    // 48*1440*2 = 138,240
  const size_t W1e = Wxe + (size_t)48 * KTOT * 2;
  float* Bc0 = (float*)(ws + W1e);                    // 2048
  float* Bc1 = (float*)(ws + W1e + 2048);             // 192
  int* flag = (int*)(ws + W1e + 2048 + 192);          // total ~105 MiB

  hipMemsetAsync(ws, 0, zpe, stream);                 // P pair + C0 + C1 + zero page
  detect_dtype<<<1, 64, 0, stream>>>((const unsigned short*)W0, flag);
  canon_b<<<3, 256, 0, stream>>>(b0, b1, Bc0, Bc1, flag);
  prep_w0<<<(512 * KT0 + 255) / 256, 256, 0, stream>>>(W0, Wp0, flag);
  prep_wx<<<32, 256, 0, stream>>>(W0, Wx0, flag);
  prep_w1<<<(48 * KTOT + 255) / 256, 256, 0, stream>>>(W1, Wp1, flag);
  prep_xtap<<<3072, 256, 0, stream>>>(hist, Xtap, flag);

  for (int t = 0; t < 12; ++t) {
    gemm_gate0<<<1024, 256, 0, stream>>>(P[t & 1], P[(t + 1) & 1], Wp0, Wx0, Bc0, C0,
                                         Xtap, zp, t);
    gemm_gate1<<<512, 256, 0, stream>>>(P[(t + 1) & 1], P[t & 1], Wp1, Bc1, C1,
                                        d_out, zp, flag, t);
  }
}

// Round 13
// 1899.301 us; speedup vs baseline: 6.0171x; 3.9774x over previous
//
#include <hip/hip_runtime.h>
#include <hip/hip_bf16.h>

// ConvLSTM (2 layers) on MI355X. R24 = R23 with the spill fixed: gate0 keeps
// __launch_bounds__(256,2) (budget 256; R21 measured 128 -> no spill). R23's
// bounds(256,3) shrank the allocator budget to ~170 and spilled the 128-reg acc
// (VGPR_Count 84 arch + 2.2GB scratch traffic). Occupancy is a RUNTIME property
// of LDS+actual VGPR: exact-size halo rows (RSTR=2112, 50688B LDS) give 3
// blocks/CU at VGPR 128 without touching the allocator. Staging = 4 full DMA
// slices (px 0..63) + 2-px register tail (slot64=x63, slot65=0), T14-split:
// tail loads issued BEFORE the chunk's DMAs, ds_write after tap 8 (verified
// correct in R23). gate1: 33792B LDS, bounds(256,4) (budget 128 >= 52).
// All else = R21 (best, 1933us): dead-K (KT0=1152) + Xtap x-phase, 4-row M-tile
// acc 8x4, R19 spread staging, XCD stripe swizzle, zero page, tanhf.

typedef __attribute__((ext_vector_type(8))) short short8;
typedef __attribute__((ext_vector_type(4))) float float4v;

#define CS 160
#define KT0 1152          // gate0 K = 9*128 (pure h0)
#define KTOT 1440         // gate1 K = 9*160
#define RSTR 2112         // LDS halo row stride (shorts) = 66 px * 32 ch, exact
#define BSTR4 8448        // gate1 LDS buffer stride (shorts) = 4 * RSTR
#define BSTR6 12672       // gate0 LDS buffer stride (shorts) = 6 * RSTR

__device__ __forceinline__ float sigf(float x) { return 1.f / (1.f + __expf(-x)); }
__device__ __forceinline__ short f2hs(float v) {
  _Float16 h = (_Float16)v;
  return *(short*)&h;
}
__device__ __forceinline__ float bs2f(short s) {
  __hip_bfloat16 h; *(short*)&h = s; return __bfloat162float(h);
}
__device__ __forceinline__ short f2bs(float v) {
  __hip_bfloat16 h = __float2bfloat16(v);
  return *(short*)&h;
}

// async 16B global->LDS; per-lane lds ptr must equal uniform_base + lane*16
__device__ __forceinline__ void async_ld16(const short* g, short* l) {
  __builtin_amdgcn_global_load_lds(
      (const __attribute__((address_space(1))) unsigned int*)g,
      (__attribute__((address_space(3))) unsigned int*)l, 16, 0, 0);
}

// One 64-lane DMA slice (j in 0..3) covering LDS slots px = j*16 .. j*16+15
// (all interior: xx = px-1 in [-1,62]; xx=-1 reads zero page).
__device__ __forceinline__ void stage_one4(const short* __restrict__ rowPtr, bool rowOK,
                                           short* dstRow, int lane,
                                           const short* __restrict__ zp, int j) {
  int e = j * 64 + lane;
  int px = e >> 2, v = e & 3;
  int xx = px - 1;
  bool ok = rowOK && (xx >= 0);
  const short* g = ok ? (rowPtr + (size_t)xx * CS + v * 8) : zp;
  async_ld16(g, dstRow + e * 8);
}

// Full 4-slice interior stage (prologue helper).
__device__ __forceinline__ void stage_row4(const short* __restrict__ rowPtr, bool rowOK,
                                           short* dstRow, int lane,
                                           const short* __restrict__ zp) {
  #pragma unroll
  for (int j = 0; j < 4; ++j) stage_one4(rowPtr, rowOK, dstRow, lane, zp, j);
}

// Tail load (call BEFORE issuing the chunk's DMA slices): lanes 0..3 load slot64
// (= global x 63) ch-group lane; others zero. Slot 65 is always zero.
__device__ __forceinline__ short8 tail_load(const short* __restrict__ srcChunk,
                                            bool rowOK, int lane) {
  short8 tv = {0, 0, 0, 0, 0, 0, 0, 0};
  if (lane < 4 && rowOK) tv = *(const short8*)(srcChunk + (size_t)63 * CS + lane * 8);
  return tv;
}

// Tail write (call after last consumption of the previous buffer, before barrier).
__device__ __forceinline__ void tail_write(short* dstRow, int lane, short8 tv) {
  if (lane < 8) {
    short8 w = {0, 0, 0, 0, 0, 0, 0, 0};
    if (lane < 4) w = tv;
    *(short8*)(dstRow + (64 + (lane >> 2)) * 32 + (lane & 3) * 8) = w;
  }
}

// ---- dtype detect: fp32 low-halves have uniform bits[14:7]; bf16 weights cluster ----
__global__ void detect_dtype(const unsigned short* __restrict__ w0, int* __restrict__ flag) {
  int lane = threadIdx.x;
  int cnt = 0;
  for (int i = 0; i < 4; ++i) {
    unsigned short u = w0[2 * (lane + 64 * i)];
    int e = (u >> 7) & 0xFF;
    unsigned long long b = __ballot(e >= 0xC0);
    cnt += __popcll(b);
  }
  if (lane == 0) *flag = (cnt > 32) ? 1 : 0;   // 1 = fp32 inputs
}

__global__ void canon_b(const void* __restrict__ b0, const void* __restrict__ b1,
                        float* __restrict__ Bc0, float* __restrict__ Bc1,
                        const int* __restrict__ flag) {
  int i = blockIdx.x * 256 + threadIdx.x;
  int fl = *flag;
  if (i < 512) {
    float v = fl ? ((const float*)b0)[i] : bs2f(((const short*)b0)[i]);
    if (!isfinite(v) || fabsf(v) > 1e4f) v = 0.f;
    Bc0[i] = v;
  } else if (i < 560) {
    int j = i - 512;
    float v = fl ? ((const float*)b1)[j] : bs2f(((const short*)b1)[j]);
    if (!isfinite(v) || fabsf(v) > 1e4f) v = 0.f;
    Bc1[j] = v;
  }
}

__device__ __forceinline__ float ldw(const void* W, int idx, int fl) {
  float w = fl ? ((const float*)W)[idx] : bs2f(((const short*)W)[idx]);
  if (!isfinite(w) || fabsf(w) > 1e4f) w = 0.f;
  return w;
}

// layer0 h0 weights: Wp0[co][tap*128+c] = W0[co][1+c][tap]  (512 x 1152)
__global__ void prep_w0(const void* __restrict__ W0, short* __restrict__ Wp,
                        const int* __restrict__ flag) {
  int i = blockIdx.x * 256 + threadIdx.x;
  if (i >= 512 * KT0) return;
  int fl = *flag;
  int co = i / KT0, k = i - co * KT0;
  int tap = k >> 7, c = k & 127;
  Wp[i] = f2hs(ldw(W0, (co * 129 + 1 + c) * 9 + tap, fl));
}

// layer0 x weights: Wx[co][16], k<9 -> W0[co][0][k], else 0  (512 x 16)
__global__ void prep_wx(const void* __restrict__ W0, short* __restrict__ Wx,
                        const int* __restrict__ flag) {
  int i = blockIdx.x * 256 + threadIdx.x;
  if (i >= 512 * 16) return;
  int fl = *flag;
  int co = i >> 4, k = i & 15;
  float w = (k < 9) ? ldw(W0, (co * 129) * 9 + k, fl) : 0.f;
  Wx[i] = f2hs(w);
}

// layer1 weights: Wp1[co][tap*160+c]: c<140 -> W1[co][c][tap] (h0 at P-ch0..127,
// h1 at P-ch128..139), else 0.  (48 x 1440)
__global__ void prep_w1(const void* __restrict__ W1, short* __restrict__ Wp,
                        const int* __restrict__ flag) {
  int i = blockIdx.x * 256 + threadIdx.x;
  if (i >= 48 * KTOT) return;
  int fl = *flag;
  int co = i / KTOT, k = i - co * KTOT;
  int tap = k / CS, c = k - tap * CS;
  float w = (c < 140) ? ldw(W1, (co * 140 + c) * 9 + tap, fl) : 0.f;
  Wp[i] = f2hs(w);
}

// Xtap[t][p][16]: k<9 = sanitized x[t] at tap-shifted pixel (0 at borders), k>=9 = 0.
__global__ void prep_xtap(const void* __restrict__ hist, short* __restrict__ Xtap,
                          const int* __restrict__ flag) {
  int i = blockIdx.x * 256 + threadIdx.x;      // < 786432 = 12*65536
  int t = i >> 16, p = i & 65535;
  int b = p >> 12, pix = p & 4095, y = pix >> 6, x = pix & 63;
  int fl = *flag;
  short8 lo = {0, 0, 0, 0, 0, 0, 0, 0}, hi = {0, 0, 0, 0, 0, 0, 0, 0};
  #pragma unroll
  for (int k = 0; k < 9; ++k) {
    int dy = k / 3, dx = k - dy * 3;
    int yy = y + dy - 1, xx = x + dx - 1;
    float f = 0.f;
    if (yy >= 0 && yy < 64 && xx >= 0 && xx < 64) {
      int hidx = (b * 12 + t) * 4096 + yy * 64 + xx;
      f = fl ? ((const float*)hist)[hidx] : bs2f(((const short*)hist)[hidx]);
      if (!isfinite(f) || fabsf(f) > 1e4f) f = 0.f;
    }
    if (k < 8) lo[k] = f2hs(f); else hi[k - 8] = f2hs(f);
  }
  *(short8*)(Xtap + (size_t)i * 16) = lo;
  *(short8*)(Xtap + (size_t)i * 16 + 8) = hi;
}

// ---- layer 0: M=256px (4 rows) x N=128co. Grid = 4 nt * 256 mt = 1024. ----
__global__ __launch_bounds__(256, 2) void gemm_gate0(
    const short* __restrict__ Pcur, short* __restrict__ Pnext,
    const short* __restrict__ Wp, const short* __restrict__ Wx,
    const float* __restrict__ Bc0, float* __restrict__ C0,
    const short* __restrict__ Xtap, const short* __restrict__ zp, int t) {
  // XCD stripe swizzle: XCD x owns mt in [32x,32x+32) (= 2 batches of P) for ALL nt.
  int pbx = blockIdx.x;
  int xcd = pbx & 7, i = pbx >> 3;             // i 0..127
  int mt = xcd * 32 + (i & 31);                // 0..255
  int nt = i >> 5;                             // 0..3
  int b = mt >> 4, y0 = (mt & 15) * 4;
  int tid = threadIdx.x, wave = tid >> 6, lane = tid & 63;
  int ln15 = lane & 15, quad = lane >> 4;
  int wm = wave & 1, wn = wave >> 1;           // wave tile: rows [wm*2, wm*2+1], co half wn
  int hc = nt * 32 + wn * 16 + ln15;

  __shared__ __align__(16) short halo[2 * BSTR6];   // dbuf, 50688 B -> 3 blocks/CU

  float4v acc[8][4];
  #pragma unroll
  for (int i2 = 0; i2 < 8; ++i2)
    #pragma unroll
    for (int j = 0; j < 4; ++j) acc[i2][j] = (float4v){0.f, 0.f, 0.f, 0.f};

  // B frag addr (g, tap, c0): wbase + g*128*KT0 + tap*128 + c0
  const short* wbase = Wp + (size_t)hc * KT0 + quad * 8;
  short8 bcur[4], bnxt[4];
  #pragma unroll
  for (int g = 0; g < 4; ++g)
    bcur[g] = *(const short8*)(wbase + (size_t)g * 128 * KT0);

  // 6 halo rows (y0-1 .. y0+4): wave w stages LDS row w; waves 0,1 also rows 4,5.
  int yyA = y0 - 1 + wave;
  bool okA = (yyA >= 0) && (yyA < 64);
  const short* baseA = Pcur + (size_t)((b * 64 + yyA) * 64) * CS;
  int yyB = y0 + 3 + wave;                     // rows 4,5 (waves 0,1 only)
  bool okB = (wave < 2) && (yyB < 64);
  const short* baseB = Pcur + (size_t)((b * 64 + yyB) * 64) * CS;

  // x-phase operand loads + prologue tail loads FIRST (before any DMA in the FIFO).
  bool hiQ = quad >= 2;
  short8 ax[8], bxr[4];
  #pragma unroll
  for (int mf = 0; mf < 8; ++mf) {
    int row = y0 + wm * 2 + (mf >> 2);
    int pixB = (b * 64 + row) * 64 + (mf & 3) * 16 + ln15;
    ax[mf] = *(const short8*)(Xtap + ((size_t)t * 65536 + pixB) * 16 + (quad & 1) * 8);
  }
  #pragma unroll
  for (int g = 0; g < 4; ++g) {
    const short* wxp = Wx + (size_t)(g * 128 + hc) * 16 + (quad & 1) * 8;
    bxr[g] = *(const short8*)(hiQ ? zp : wxp);
  }
  short8 tA = tail_load(baseA, okA, lane);
  short8 tB = tail_load(baseB, okB, lane);

  stage_row4(baseA, okA, halo + wave * RSTR, lane, zp);
  if (wave < 2) stage_row4(baseB, okB, halo + (4 + wave) * RSTR, lane, zp);

  // tap-packed x phase: K=32 MFMA, k=taps (0..8 live); runs while DMAs fly.
  #pragma unroll
  for (int g = 0; g < 4; ++g)
    #pragma unroll
    for (int mf = 0; mf < 8; ++mf)
      acc[mf][g] = __builtin_amdgcn_mfma_f32_16x16x32_f16(ax[mf], bxr[g], acc[mf][g], 0, 0, 0);

  tail_write(halo + wave * RSTR, lane, tA);
  if (wave < 2) tail_write(halo + (4 + wave) * RSTR, lane, tB);
  __syncthreads();

  for (int ch = 0; ch < 4; ++ch) {
    int c0 = ch * 32;
    const short* cur = halo + (ch & 1) * BSTR6;
    short* nd = halo + ((ch + 1) & 1) * BSTR6;
    const short* srcA = baseA + c0 + 32;
    const short* srcB = baseB + c0 + 32;
    // tail loads for next chunk issued BEFORE this chunk's DMA slices (T14 split):
    // their vmcnt wait at tail_write drains nothing staged this chunk.
    short8 nA = {0, 0, 0, 0, 0, 0, 0, 0}, nB = {0, 0, 0, 0, 0, 0, 0, 0};
    if (ch < 3) {
      nA = tail_load(srcA, okA, lane);
      if (wave < 2) nB = tail_load(srcB, okB, lane);
    }
    #pragma unroll
    for (int tap = 0; tap < 9; ++tap) {
      int dy = tap / 3, dx = tap - dy * 3;
      // spread staging (R19): one DMA slice per tap, taps 0..3
      if (ch < 3 && tap < 4) {
        stage_one4(srcA, okA, nd + wave * RSTR, lane, zp, tap);
        if (wave < 2) stage_one4(srcB, okB, nd + (4 + wave) * RSTR, lane, zp, tap);
      }
      // prefetch next tap's (or next chunk's tap-0) B fragments
      int ntap = (tap < 8) ? tap + 1 : 0;
      int nc0 = (tap < 8) ? c0 : ((ch < 3) ? c0 + 32 : c0);
      #pragma unroll
      for (int g = 0; g < 4; ++g)
        bnxt[g] = *(const short8*)(wbase + (size_t)g * 128 * KT0 + ntap * 128 + nc0);

      short8 af[8];
      #pragma unroll
      for (int mf = 0; mf < 8; ++mf)
        af[mf] = *(const short8*)&cur[(wm * 2 + (mf >> 2) + dy) * RSTR
                                      + ((mf & 3) * 16 + ln15 + dx) * 32 + quad * 8];
      #pragma unroll
      for (int g = 0; g < 4; ++g)
        #pragma unroll
        for (int mf = 0; mf < 8; ++mf)
          acc[mf][g] = __builtin_amdgcn_mfma_f32_16x16x32_f16(af[mf], bcur[g], acc[mf][g], 0, 0, 0);
      #pragma unroll
      for (int g = 0; g < 4; ++g) bcur[g] = bnxt[g];
    }
    if (ch < 3) {
      tail_write(nd + wave * RSTR, lane, nA);
      if (wave < 2) tail_write(nd + (4 + wave) * RSTR, lane, nB);
    }
    __syncthreads();
  }

  // epilogue: all 4 gates in-register per (pix,hc); 8 mf = 2 rows x 4 x-frags.
  float bi = Bc0[hc], bff = Bc0[128 + hc], bo = Bc0[256 + hc], bg = Bc0[384 + hc];
  #pragma unroll
  for (int mf = 0; mf < 8; ++mf) {
    int row = y0 + wm * 2 + (mf >> 2);
    int pixRow = (b * 64 + row) * 64;
    #pragma unroll
    for (int r = 0; r < 4; ++r) {
      int x = (mf & 3) * 16 + quad * 4 + r;    // C/D row = quad*4 + reg
      int pix = pixRow + x;
      float zi = acc[mf][0][r] + bi;
      float zf = acc[mf][1][r] + bff;
      float zo = acc[mf][2][r] + bo;
      float zg = acc[mf][3][r] + bg;
      float cprev = C0[(size_t)pix * 128 + hc];
      float cn = sigf(zf) * cprev + sigf(zi) * tanhf(zg);
      float hn = sigf(zo) * tanhf(cn);
      C0[(size_t)pix * 128 + hc] = cn;
      Pnext[(size_t)pix * CS + hc] = f2hs(hn);
    }
  }
}

// ---- layer 1: M=128px (2 rows) x N=48co. Grid 512. B register-prefetch. ----
__global__ __launch_bounds__(256, 4) void gemm_gate1(
    const short* __restrict__ Prd, short* __restrict__ Pwr,
    const short* __restrict__ Wp, const float* __restrict__ Bc1,
    float* __restrict__ C1, void* __restrict__ outp,
    const short* __restrict__ zp, const int* __restrict__ flagp, int t) {
  // XCD stripe swizzle: XCD x owns bid in [64x, 64x+64) = 2 batches (L2-fit halos).
  int pbx = blockIdx.x;
  int bid = (pbx & 7) * 64 + (pbx >> 3);
  int b = bid >> 5, y0 = (bid & 31) * 2;
  int tid = threadIdx.x, wave = tid >> 6, lane = tid & 63;
  int ln15 = lane & 15, quad = lane >> 4;
  int wr = wave >> 1, wh = wave & 1;
  int flagv = *flagp;

  __shared__ __align__(16) short halo[2 * BSTR4];   // 33792 B

  float4v acc[2][3];
  #pragma unroll
  for (int i = 0; i < 2; ++i)
    #pragma unroll
    for (int j = 0; j < 3; ++j) acc[i][j] = (float4v){0.f, 0.f, 0.f, 0.f};

  int yy = y0 - 1 + wave;
  bool rowOK = (yy >= 0) && (yy < 64);
  const short* rowBase = Prd + (size_t)((b * 64 + yy) * 64) * CS;

  const short* wbase = Wp + (size_t)ln15 * KTOT + quad * 8;
  short8 bcur[3], bnxt[3];
  #pragma unroll
  for (int nf = 0; nf < 3; ++nf)
    bcur[nf] = *(const short8*)(wbase + (size_t)nf * 16 * KTOT);

  short8 tP = tail_load(rowBase, rowOK, lane);
  stage_row4(rowBase, rowOK, halo + wave * RSTR, lane, zp);
  tail_write(halo + wave * RSTR, lane, tP);
  __syncthreads();

  for (int ch = 0; ch < 5; ++ch) {
    int c0 = ch * 32;
    const short* cur = halo + (ch & 1) * BSTR4;
    short* nxtDst = halo + ((ch + 1) & 1) * BSTR4 + wave * RSTR;
    const short* nxtSrc = rowBase + c0 + 32;
    short8 nP = {0, 0, 0, 0, 0, 0, 0, 0};
    if (ch < 4) nP = tail_load(nxtSrc, rowOK, lane);
    #pragma unroll
    for (int tap = 0; tap < 9; ++tap) {
      int dy = tap / 3, dx = tap - dy * 3;
      if (ch < 4 && tap < 4)
        stage_one4(nxtSrc, rowOK, nxtDst, lane, zp, tap);
      int ntap = (tap < 8) ? tap + 1 : 0;
      int nc0 = (tap < 8) ? c0 : ((ch < 4) ? c0 + 32 : c0);
      #pragma unroll
      for (int nf = 0; nf < 3; ++nf)
        bnxt[nf] = *(const short8*)(wbase + (size_t)nf * 16 * KTOT + ntap * CS + nc0);

      short8 af[2];
      #pragma unroll
      for (int mf = 0; mf < 2; ++mf)
        af[mf] = *(const short8*)&cur[(wr + dy) * RSTR + (wh * 32 + mf * 16 + ln15 + dx) * 32
                                      + quad * 8];
      #pragma unroll
      for (int nf = 0; nf < 3; ++nf)
        #pragma unroll
        for (int mf = 0; mf < 2; ++mf)
          acc[mf][nf] = __builtin_amdgcn_mfma_f32_16x16x32_f16(af[mf], bcur[nf], acc[mf][nf], 0, 0, 0);
      #pragma unroll
      for (int nf = 0; nf < 3; ++nf) bcur[nf] = bnxt[nf];
    }
    if (ch < 4) tail_write(nxtDst, lane, nP);
    __syncthreads();
  }

  // z -> LDS (reuse halo: 128*48 fp32 = 24576 B <= 33792), then gate pass
  float* zbuf = (float*)halo;
  #pragma unroll
  for (int mf = 0; mf < 2; ++mf)
    #pragma unroll
    for (int nf = 0; nf < 3; ++nf)
      #pragma unroll
      for (int r = 0; r < 4; ++r) {
        int pxl = wr * 64 + wh * 32 + mf * 16 + quad * 4 + r;
        zbuf[pxl * 48 + nf * 16 + ln15] = acc[mf][nf][r];
      }
  __syncthreads();

  #pragma unroll
  for (int k = 0; k < 6; ++k) {
    int id = k * 256 + tid;
    int hc = id >> 7, pxl = id & 127;
    float zi = zbuf[pxl * 48 + hc]      + Bc1[hc];
    float zf = zbuf[pxl * 48 + 12 + hc] + Bc1[12 + hc];
    float zo = zbuf[pxl * 48 + 24 + hc] + Bc1[24 + hc];
    float zg = zbuf[pxl * 48 + 36 + hc] + Bc1[36 + hc];
    int y = y0 + (pxl >> 6), x = pxl & 63;
    int pix = (b * 64 + y) * 64 + x;
    float cprev = C1[(size_t)pix * 12 + hc];
    float cn = sigf(zf) * cprev + sigf(zi) * tanhf(zg);
    float hn = sigf(zo) * tanhf(cn);
    C1[(size_t)pix * 12 + hc] = cn;
    Pwr[(size_t)pix * CS + 128 + hc] = f2hs(hn);   // h1 at ch128..139
    if (t == 11) {
      int oidx = (b * 12 + hc) * 4096 + y * 64 + x;
      if (flagv) ((float*)outp)[oidx] = hn;
      else ((short*)outp)[oidx] = f2bs(hn);
    }
  }
}

extern "C" void kernel_launch(void* const* d_in, const int* in_sizes, int n_in,
                              void* d_out, int out_size, void* d_ws, size_t ws_size,
                              hipStream_t stream) {
  const void* hist = d_in[0];                  // (16,12,4096,1)
  const void* W0 = d_in[2];                    // (512,129,3,3)
  const void* b0 = d_in[3];
  const void* W1 = d_in[4];                    // (48,140,3,3)
  const void* b1 = d_in[5];

  char* ws = (char*)d_ws;
  const size_t PszB = (size_t)16 * 4096 * CS * 2;     // 20,971,520
  short* P[2] = {(short*)ws, (short*)(ws + PszB)};
  float* C0 = (float*)(ws + 2 * PszB);                // 33,554,432
  const size_t C0e = 2 * PszB + 33554432;
  float* C1 = (float*)(ws + C0e);                     // 3,145,728
  const size_t C1e = C0e + 3145728;
  short* zp = (short*)(ws + C1e);                     // 256 B zero page
  const size_t zpe = C1e + 256;                       // memset to here
  short* Xtap = (short*)(ws + zpe);                   // 12*65536*16*2 = 25,165,824
  const size_t Xte = zpe + (size_t)12 * 65536 * 16 * 2;
  short* Wp0 = (short*)(ws + Xte);                    // 512*1152*2 = 1,179,648
  const size_t W0e = Xte + (size_t)512 * KT0 * 2;
  short* Wx0 = (short*)(ws + W0e);                    // 512*16*2 = 16,384
  const size_t Wxe = W0e + 512 * 16 * 2;
  short* Wp1 = (short*)(ws + Wxe);                    // 48*1440*2 = 138,240
  const size_t W1e = Wxe + (size_t)48 * KTOT * 2;
  float* Bc0 = (float*)(ws + W1e);                    // 2048
  float* Bc1 = (float*)(ws + W1e + 2048);             // 192
  int* flag = (int*)(ws + W1e + 2048 + 192);          // total ~105 MiB

  hipMemsetAsync(ws, 0, zpe, stream);                 // P pair + C0 + C1 + zero page
  detect_dtype<<<1, 64, 0, stream>>>((const unsigned short*)W0, flag);
  canon_b<<<3, 256, 0, stream>>>(b0, b1, Bc0, Bc1, flag);
  prep_w0<<<(512 * KT0 + 255) / 256, 256, 0, stream>>>(W0, Wp0, flag);
  prep_wx<<<32, 256, 0, stream>>>(W0, Wx0, flag);
  prep_w1<<<(48 * KTOT + 255) / 256, 256, 0, stream>>>(W1, Wp1, flag);
  prep_xtap<<<3072, 256, 0, stream>>>(hist, Xtap, flag);

  for (int t = 0; t < 12; ++t) {
    gemm_gate0<<<1024, 256, 0, stream>>>(P[t & 1], P[(t + 1) & 1], Wp0, Wx0, Bc0, C0,
                                         Xtap, zp, t);
    gemm_gate1<<<512, 256, 0, stream>>>(P[(t + 1) & 1], P[t & 1], Wp1, Bc1, C1,
                                        d_out, zp, flag, t);
  }
}

// Round 14
// 1812.460 us; speedup vs baseline: 6.3054x; 1.0479x over previous
//
#include <hip/hip_runtime.h>
#include <hip/hip_bf16.h>

// ConvLSTM (2 layers) on MI355X. R25 = R24 (best, 1899us) + gate1 tap-parity K-split.
// R24 finding: gate0 occupancy is wedged at 8 waves/CU by the UNIFIED VGPR+AGPR file
// (128 arch + 128 acc = 256/wave); LDS shrink didn't move it. gate0 accepted at
// ~129.5us. gate1 is the disproportionate cost: 11.4% of gate0's FLOPs but ~25us
// (should be ~15): wave tile 32px x 48co = 6 MFMA/tap vs 3 B-loads (no latency
// cover), B duplicated 4x. R25 gate1: wave = (w=row, kp=tap-parity). Each wave:
// 64px x 48co (acc 4x3, af[4]), taps with (ch*9+tap) % 2 == kp -> 12 MFMA/wave-tap,
// B prefetch 2 taps ahead, B dup 2x. Partial sums merged in zbuf (kp0 writes,
// barrier, kp1 adds). Grid/block/LDS unchanged -> TLP preserved (8 waves/CU).
// All else = R24: dead-K gate0 (KT0=1152) + Xtap x-phase, 4-row M-tile acc 8x4,
// exact-size LDS rows + T14 register tails, R19 spread staging, XCD stripe
// swizzle, zero page, bounds(256,2), tanhf.

typedef __attribute__((ext_vector_type(8))) short short8;
typedef __attribute__((ext_vector_type(4))) float float4v;

#define CS 160
#define KT0 1152          // gate0 K = 9*128 (pure h0)
#define KTOT 1440         // gate1 K = 9*160
#define RSTR 2112         // LDS halo row stride (shorts) = 66 px * 32 ch, exact
#define BSTR4 8448        // gate1 LDS buffer stride (shorts) = 4 * RSTR
#define BSTR6 12672       // gate0 LDS buffer stride (shorts) = 6 * RSTR

__device__ __forceinline__ float sigf(float x) { return 1.f / (1.f + __expf(-x)); }
__device__ __forceinline__ short f2hs(float v) {
  _Float16 h = (_Float16)v;
  return *(short*)&h;
}
__device__ __forceinline__ float bs2f(short s) {
  __hip_bfloat16 h; *(short*)&h = s; return __bfloat162float(h);
}
__device__ __forceinline__ short f2bs(float v) {
  __hip_bfloat16 h = __float2bfloat16(v);
  return *(short*)&h;
}

// async 16B global->LDS; per-lane lds ptr must equal uniform_base + lane*16
__device__ __forceinline__ void async_ld16(const short* g, short* l) {
  __builtin_amdgcn_global_load_lds(
      (const __attribute__((address_space(1))) unsigned int*)g,
      (__attribute__((address_space(3))) unsigned int*)l, 16, 0, 0);
}

// One 64-lane DMA slice (j in 0..3) covering LDS slots px = j*16 .. j*16+15
// (all interior: xx = px-1 in [-1,62]; xx=-1 reads zero page).
__device__ __forceinline__ void stage_one4(const short* __restrict__ rowPtr, bool rowOK,
                                           short* dstRow, int lane,
                                           const short* __restrict__ zp, int j) {
  int e = j * 64 + lane;
  int px = e >> 2, v = e & 3;
  int xx = px - 1;
  bool ok = rowOK && (xx >= 0);
  const short* g = ok ? (rowPtr + (size_t)xx * CS + v * 8) : zp;
  async_ld16(g, dstRow + e * 8);
}

// Full 4-slice interior stage (prologue helper).
__device__ __forceinline__ void stage_row4(const short* __restrict__ rowPtr, bool rowOK,
                                           short* dstRow, int lane,
                                           const short* __restrict__ zp) {
  #pragma unroll
  for (int j = 0; j < 4; ++j) stage_one4(rowPtr, rowOK, dstRow, lane, zp, j);
}

// Tail load (call BEFORE issuing the chunk's DMA slices): lanes 0..3 load slot64
// (= global x 63) ch-group lane; others zero. Slot 65 is always zero.
__device__ __forceinline__ short8 tail_load(const short* __restrict__ srcChunk,
                                            bool rowOK, int lane) {
  short8 tv = {0, 0, 0, 0, 0, 0, 0, 0};
  if (lane < 4 && rowOK) tv = *(const short8*)(srcChunk + (size_t)63 * CS + lane * 8);
  return tv;
}

// Tail write (call after last consumption of the previous buffer, before barrier).
__device__ __forceinline__ void tail_write(short* dstRow, int lane, short8 tv) {
  if (lane < 8) {
    short8 w = {0, 0, 0, 0, 0, 0, 0, 0};
    if (lane < 4) w = tv;
    *(short8*)(dstRow + (64 + (lane >> 2)) * 32 + (lane & 3) * 8) = w;
  }
}

// ---- dtype detect: fp32 low-halves have uniform bits[14:7]; bf16 weights cluster ----
__global__ void detect_dtype(const unsigned short* __restrict__ w0, int* __restrict__ flag) {
  int lane = threadIdx.x;
  int cnt = 0;
  for (int i = 0; i < 4; ++i) {
    unsigned short u = w0[2 * (lane + 64 * i)];
    int e = (u >> 7) & 0xFF;
    unsigned long long b = __ballot(e >= 0xC0);
    cnt += __popcll(b);
  }
  if (lane == 0) *flag = (cnt > 32) ? 1 : 0;   // 1 = fp32 inputs
}

__global__ void canon_b(const void* __restrict__ b0, const void* __restrict__ b1,
                        float* __restrict__ Bc0, float* __restrict__ Bc1,
                        const int* __restrict__ flag) {
  int i = blockIdx.x * 256 + threadIdx.x;
  int fl = *flag;
  if (i < 512) {
    float v = fl ? ((const float*)b0)[i] : bs2f(((const short*)b0)[i]);
    if (!isfinite(v) || fabsf(v) > 1e4f) v = 0.f;
    Bc0[i] = v;
  } else if (i < 560) {
    int j = i - 512;
    float v = fl ? ((const float*)b1)[j] : bs2f(((const short*)b1)[j]);
    if (!isfinite(v) || fabsf(v) > 1e4f) v = 0.f;
    Bc1[j] = v;
  }
}

__device__ __forceinline__ float ldw(const void* W, int idx, int fl) {
  float w = fl ? ((const float*)W)[idx] : bs2f(((const short*)W)[idx]);
  if (!isfinite(w) || fabsf(w) > 1e4f) w = 0.f;
  return w;
}

// layer0 h0 weights: Wp0[co][tap*128+c] = W0[co][1+c][tap]  (512 x 1152)
__global__ void prep_w0(const void* __restrict__ W0, short* __restrict__ Wp,
                        const int* __restrict__ flag) {
  int i = blockIdx.x * 256 + threadIdx.x;
  if (i >= 512 * KT0) return;
  int fl = *flag;
  int co = i / KT0, k = i - co * KT0;
  int tap = k >> 7, c = k & 127;
  Wp[i] = f2hs(ldw(W0, (co * 129 + 1 + c) * 9 + tap, fl));
}

// layer0 x weights: Wx[co][16], k<9 -> W0[co][0][k], else 0  (512 x 16)
__global__ void prep_wx(const void* __restrict__ W0, short* __restrict__ Wx,
                        const int* __restrict__ flag) {
  int i = blockIdx.x * 256 + threadIdx.x;
  if (i >= 512 * 16) return;
  int fl = *flag;
  int co = i >> 4, k = i & 15;
  float w = (k < 9) ? ldw(W0, (co * 129) * 9 + k, fl) : 0.f;
  Wx[i] = f2hs(w);
}

// layer1 weights: Wp1[co][tap*160+c]: c<140 -> W1[co][c][tap] (h0 at P-ch0..127,
// h1 at P-ch128..139), else 0.  (48 x 1440)
__global__ void prep_w1(const void* __restrict__ W1, short* __restrict__ Wp,
                        const int* __restrict__ flag) {
  int i = blockIdx.x * 256 + threadIdx.x;
  if (i >= 48 * KTOT) return;
  int fl = *flag;
  int co = i / KTOT, k = i - co * KTOT;
  int tap = k / CS, c = k - tap * CS;
  float w = (c < 140) ? ldw(W1, (co * 140 + c) * 9 + tap, fl) : 0.f;
  Wp[i] = f2hs(w);
}

// Xtap[t][p][16]: k<9 = sanitized x[t] at tap-shifted pixel (0 at borders), k>=9 = 0.
__global__ void prep_xtap(const void* __restrict__ hist, short* __restrict__ Xtap,
                          const int* __restrict__ flag) {
  int i = blockIdx.x * 256 + threadIdx.x;      // < 786432 = 12*65536
  int t = i >> 16, p = i & 65535;
  int b = p >> 12, pix = p & 4095, y = pix >> 6, x = pix & 63;
  int fl = *flag;
  short8 lo = {0, 0, 0, 0, 0, 0, 0, 0}, hi = {0, 0, 0, 0, 0, 0, 0, 0};
  #pragma unroll
  for (int k = 0; k < 9; ++k) {
    int dy = k / 3, dx = k - dy * 3;
    int yy = y + dy - 1, xx = x + dx - 1;
    float f = 0.f;
    if (yy >= 0 && yy < 64 && xx >= 0 && xx < 64) {
      int hidx = (b * 12 + t) * 4096 + yy * 64 + xx;
      f = fl ? ((const float*)hist)[hidx] : bs2f(((const short*)hist)[hidx]);
      if (!isfinite(f) || fabsf(f) > 1e4f) f = 0.f;
    }
    if (k < 8) lo[k] = f2hs(f); else hi[k - 8] = f2hs(f);
  }
  *(short8*)(Xtap + (size_t)i * 16) = lo;
  *(short8*)(Xtap + (size_t)i * 16 + 8) = hi;
}

// ---- layer 0: M=256px (4 rows) x N=128co. Grid = 4 nt * 256 mt = 1024. (= R24) ----
__global__ __launch_bounds__(256, 2) void gemm_gate0(
    const short* __restrict__ Pcur, short* __restrict__ Pnext,
    const short* __restrict__ Wp, const short* __restrict__ Wx,
    const float* __restrict__ Bc0, float* __restrict__ C0,
    const short* __restrict__ Xtap, const short* __restrict__ zp, int t) {
  // XCD stripe swizzle: XCD x owns mt in [32x,32x+32) (= 2 batches of P) for ALL nt.
  int pbx = blockIdx.x;
  int xcd = pbx & 7, i = pbx >> 3;             // i 0..127
  int mt = xcd * 32 + (i & 31);                // 0..255
  int nt = i >> 5;                             // 0..3
  int b = mt >> 4, y0 = (mt & 15) * 4;
  int tid = threadIdx.x, wave = tid >> 6, lane = tid & 63;
  int ln15 = lane & 15, quad = lane >> 4;
  int wm = wave & 1, wn = wave >> 1;           // wave tile: rows [wm*2, wm*2+1], co half wn
  int hc = nt * 32 + wn * 16 + ln15;

  __shared__ __align__(16) short halo[2 * BSTR6];   // dbuf, 50688 B

  float4v acc[8][4];
  #pragma unroll
  for (int i2 = 0; i2 < 8; ++i2)
    #pragma unroll
    for (int j = 0; j < 4; ++j) acc[i2][j] = (float4v){0.f, 0.f, 0.f, 0.f};

  // B frag addr (g, tap, c0): wbase + g*128*KT0 + tap*128 + c0
  const short* wbase = Wp + (size_t)hc * KT0 + quad * 8;
  short8 bcur[4], bnxt[4];
  #pragma unroll
  for (int g = 0; g < 4; ++g)
    bcur[g] = *(const short8*)(wbase + (size_t)g * 128 * KT0);

  // 6 halo rows (y0-1 .. y0+4): wave w stages LDS row w; waves 0,1 also rows 4,5.
  int yyA = y0 - 1 + wave;
  bool okA = (yyA >= 0) && (yyA < 64);
  const short* baseA = Pcur + (size_t)((b * 64 + yyA) * 64) * CS;
  int yyB = y0 + 3 + wave;                     // rows 4,5 (waves 0,1 only)
  bool okB = (wave < 2) && (yyB < 64);
  const short* baseB = Pcur + (size_t)((b * 64 + yyB) * 64) * CS;

  // x-phase operand loads + prologue tail loads FIRST (before any DMA in the FIFO).
  bool hiQ = quad >= 2;
  short8 ax[8], bxr[4];
  #pragma unroll
  for (int mf = 0; mf < 8; ++mf) {
    int row = y0 + wm * 2 + (mf >> 2);
    int pixB = (b * 64 + row) * 64 + (mf & 3) * 16 + ln15;
    ax[mf] = *(const short8*)(Xtap + ((size_t)t * 65536 + pixB) * 16 + (quad & 1) * 8);
  }
  #pragma unroll
  for (int g = 0; g < 4; ++g) {
    const short* wxp = Wx + (size_t)(g * 128 + hc) * 16 + (quad & 1) * 8;
    bxr[g] = *(const short8*)(hiQ ? zp : wxp);
  }
  short8 tA = tail_load(baseA, okA, lane);
  short8 tB = tail_load(baseB, okB, lane);

  stage_row4(baseA, okA, halo + wave * RSTR, lane, zp);
  if (wave < 2) stage_row4(baseB, okB, halo + (4 + wave) * RSTR, lane, zp);

  // tap-packed x phase: K=32 MFMA, k=taps (0..8 live); runs while DMAs fly.
  #pragma unroll
  for (int g = 0; g < 4; ++g)
    #pragma unroll
    for (int mf = 0; mf < 8; ++mf)
      acc[mf][g] = __builtin_amdgcn_mfma_f32_16x16x32_f16(ax[mf], bxr[g], acc[mf][g], 0, 0, 0);

  tail_write(halo + wave * RSTR, lane, tA);
  if (wave < 2) tail_write(halo + (4 + wave) * RSTR, lane, tB);
  __syncthreads();

  for (int ch = 0; ch < 4; ++ch) {
    int c0 = ch * 32;
    const short* cur = halo + (ch & 1) * BSTR6;
    short* nd = halo + ((ch + 1) & 1) * BSTR6;
    const short* srcA = baseA + c0 + 32;
    const short* srcB = baseB + c0 + 32;
    // tail loads for next chunk issued BEFORE this chunk's DMA slices (T14 split).
    short8 nA = {0, 0, 0, 0, 0, 0, 0, 0}, nB = {0, 0, 0, 0, 0, 0, 0, 0};
    if (ch < 3) {
      nA = tail_load(srcA, okA, lane);
      if (wave < 2) nB = tail_load(srcB, okB, lane);
    }
    #pragma unroll
    for (int tap = 0; tap < 9; ++tap) {
      int dy = tap / 3, dx = tap - dy * 3;
      // spread staging (R19): one DMA slice per tap, taps 0..3
      if (ch < 3 && tap < 4) {
        stage_one4(srcA, okA, nd + wave * RSTR, lane, zp, tap);
        if (wave < 2) stage_one4(srcB, okB, nd + (4 + wave) * RSTR, lane, zp, tap);
      }
      // prefetch next tap's (or next chunk's tap-0) B fragments
      int ntap = (tap < 8) ? tap + 1 : 0;
      int nc0 = (tap < 8) ? c0 : ((ch < 3) ? c0 + 32 : c0);
      #pragma unroll
      for (int g = 0; g < 4; ++g)
        bnxt[g] = *(const short8*)(wbase + (size_t)g * 128 * KT0 + ntap * 128 + nc0);

      short8 af[8];
      #pragma unroll
      for (int mf = 0; mf < 8; ++mf)
        af[mf] = *(const short8*)&cur[(wm * 2 + (mf >> 2) + dy) * RSTR
                                      + ((mf & 3) * 16 + ln15 + dx) * 32 + quad * 8];
      #pragma unroll
      for (int g = 0; g < 4; ++g)
        #pragma unroll
        for (int mf = 0; mf < 8; ++mf)
          acc[mf][g] = __builtin_amdgcn_mfma_f32_16x16x32_f16(af[mf], bcur[g], acc[mf][g], 0, 0, 0);
      #pragma unroll
      for (int g = 0; g < 4; ++g) bcur[g] = bnxt[g];
    }
    if (ch < 3) {
      tail_write(nd + wave * RSTR, lane, nA);
      if (wave < 2) tail_write(nd + (4 + wave) * RSTR, lane, nB);
    }
    __syncthreads();
  }

  // epilogue: all 4 gates in-register per (pix,hc); 8 mf = 2 rows x 4 x-frags.
  float bi = Bc0[hc], bff = Bc0[128 + hc], bo = Bc0[256 + hc], bg = Bc0[384 + hc];
  #pragma unroll
  for (int mf = 0; mf < 8; ++mf) {
    int row = y0 + wm * 2 + (mf >> 2);
    int pixRow = (b * 64 + row) * 64;
    #pragma unroll
    for (int r = 0; r < 4; ++r) {
      int x = (mf & 3) * 16 + quad * 4 + r;    // C/D row = quad*4 + reg
      int pix = pixRow + x;
      float zi = acc[mf][0][r] + bi;
      float zf = acc[mf][1][r] + bff;
      float zo = acc[mf][2][r] + bo;
      float zg = acc[mf][3][r] + bg;
      float cprev = C0[(size_t)pix * 128 + hc];
      float cn = sigf(zf) * cprev + sigf(zi) * tanhf(zg);
      float hn = sigf(zo) * tanhf(cn);
      C0[(size_t)pix * 128 + hc] = cn;
      Pnext[(size_t)pix * CS + hc] = f2hs(hn);
    }
  }
}

// ---- layer 1: M=128px (2 rows) x N=48co. Grid 512, 256 thr. Tap-parity K-split:
// wave = (w = output row, kp = tap parity). Each wave: 64px x 48co (acc 4x3),
// taps with (ch*9+tap) parity == kp -> 12 MFMA/wave-tap, B prefetch 2 taps ahead,
// B duplication 2x (was 4x). Partials merged in zbuf (kp0 writes, kp1 adds). ----
__global__ __launch_bounds__(256, 2) void gemm_gate1(
    const short* __restrict__ Prd, short* __restrict__ Pwr,
    const short* __restrict__ Wp, const float* __restrict__ Bc1,
    float* __restrict__ C1, void* __restrict__ outp,
    const short* __restrict__ zp, const int* __restrict__ flagp, int t) {
  // XCD stripe swizzle: XCD x owns bid in [64x, 64x+64) = 2 batches (L2-fit halos).
  int pbx = blockIdx.x;
  int bid = (pbx & 7) * 64 + (pbx >> 3);
  int b = bid >> 5, y0 = (bid & 31) * 2;
  int tid = threadIdx.x, wave = tid >> 6, lane = tid & 63;
  int ln15 = lane & 15, quad = lane >> 4;
  int w = wave & 1, kp = wave >> 1;            // w: output row; kp: K-half (tap parity)
  int flagv = *flagp;

  __shared__ __align__(16) short halo[2 * BSTR4];   // 33792 B

  float4v acc[4][3];
  #pragma unroll
  for (int i = 0; i < 4; ++i)
    #pragma unroll
    for (int j = 0; j < 3; ++j) acc[i][j] = (float4v){0.f, 0.f, 0.f, 0.f};

  // staging: wave stages halo row `wave` (rows 0..3 = y0-1 .. y0+2)
  int yy = y0 - 1 + wave;
  bool rowOK = (yy >= 0) && (yy < 64);
  const short* rowBase = Prd + (size_t)((b * 64 + yy) * 64) * CS;

  const short* wbase = Wp + (size_t)ln15 * KTOT + quad * 8;
  // first own tap of chunk 0 is tap = kp (c0 = 0)
  short8 bcur[3];
  #pragma unroll
  for (int nf = 0; nf < 3; ++nf)
    bcur[nf] = *(const short8*)(wbase + (size_t)nf * 16 * KTOT + kp * CS);

  short8 tP = tail_load(rowBase, rowOK, lane);
  stage_row4(rowBase, rowOK, halo + wave * RSTR, lane, zp);
  tail_write(halo + wave * RSTR, lane, tP);
  __syncthreads();

  for (int ch = 0; ch < 5; ++ch) {
    int c0 = ch * 32;
    const short* cur = halo + (ch & 1) * BSTR4;
    short* nxtDst = halo + ((ch + 1) & 1) * BSTR4 + wave * RSTR;
    const short* nxtSrc = rowBase + c0 + 32;
    short8 nP = {0, 0, 0, 0, 0, 0, 0, 0};
    if (ch < 4) nP = tail_load(nxtSrc, rowOK, lane);
    int ts = (kp + ch * 9) & 1;                // this wave's first tap this chunk
    #pragma unroll
    for (int tt = 0; tt < 5; ++tt) {
      int tap = ts + tt * 2;
      if (tap <= 8) {
        int dy = tap / 3, dx = tap - dy * 3;
        // spread staging: one DMA slice per own-tap (tt 0..3)
        if (ch < 4 && tt < 4)
          stage_one4(nxtSrc, rowOK, nxtDst, lane, zp, tt);
        // prefetch own next tap (tap+2), crossing into next chunk when needed
        int ntap = tap + 2, nc0 = c0;
        if (ntap > 8) { ntap -= 9; nc0 = (ch < 4) ? c0 + 32 : c0; }
        short8 bnxt[3];
        #pragma unroll
        for (int nf = 0; nf < 3; ++nf)
          bnxt[nf] = *(const short8*)(wbase + (size_t)nf * 16 * KTOT + ntap * CS + nc0);

        short8 af[4];
        #pragma unroll
        for (int mf = 0; mf < 4; ++mf)
          af[mf] = *(const short8*)&cur[(w + dy) * RSTR + (mf * 16 + ln15 + dx) * 32
                                        + quad * 8];
        #pragma unroll
        for (int nf = 0; nf < 3; ++nf)
          #pragma unroll
          for (int mf = 0; mf < 4; ++mf)
            acc[mf][nf] = __builtin_amdgcn_mfma_f32_16x16x32_f16(af[mf], bcur[nf], acc[mf][nf], 0, 0, 0);
        #pragma unroll
        for (int nf = 0; nf < 3; ++nf) bcur[nf] = bnxt[nf];
      }
    }
    if (ch < 4) tail_write(nxtDst, lane, nP);
    __syncthreads();
  }

  // merge K-halves in zbuf (128px * 48 fp32 = 24576 B <= 33792), then gate pass
  float* zbuf = (float*)halo;
  if (kp == 0) {
    #pragma unroll
    for (int mf = 0; mf < 4; ++mf)
      #pragma unroll
      for (int nf = 0; nf < 3; ++nf)
        #pragma unroll
        for (int r = 0; r < 4; ++r) {
          int pxl = w * 64 + mf * 16 + quad * 4 + r;
          zbuf[pxl * 48 + nf * 16 + ln15] = acc[mf][nf][r];
        }
  }
  __syncthreads();
  if (kp == 1) {
    #pragma unroll
    for (int mf = 0; mf < 4; ++mf)
      #pragma unroll
      for (int nf = 0; nf < 3; ++nf)
        #pragma unroll
        for (int r = 0; r < 4; ++r) {
          int pxl = w * 64 + mf * 16 + quad * 4 + r;
          zbuf[pxl * 48 + nf * 16 + ln15] += acc[mf][nf][r];
        }
  }
  __syncthreads();

  #pragma unroll
  for (int k = 0; k < 6; ++k) {
    int id = k * 256 + tid;
    int hc = id >> 7, pxl = id & 127;
    float zi = zbuf[pxl * 48 + hc]      + Bc1[hc];
    float zf = zbuf[pxl * 48 + 12 + hc] + Bc1[12 + hc];
    float zo = zbuf[pxl * 48 + 24 + hc] + Bc1[24 + hc];
    float zg = zbuf[pxl * 48 + 36 + hc] + Bc1[36 + hc];
    int y = y0 + (pxl >> 6), x = pxl & 63;
    int pix = (b * 64 + y) * 64 + x;
    float cprev = C1[(size_t)pix * 12 + hc];
    float cn = sigf(zf) * cprev + sigf(zi) * tanhf(zg);
    float hn = sigf(zo) * tanhf(cn);
    C1[(size_t)pix * 12 + hc] = cn;
    Pwr[(size_t)pix * CS + 128 + hc] = f2hs(hn);   // h1 at ch128..139
    if (t == 11) {
      int oidx = (b * 12 + hc) * 4096 + y * 64 + x;
      if (flagv) ((float*)outp)[oidx] = hn;
      else ((short*)outp)[oidx] = f2bs(hn);
    }
  }
}

extern "C" void kernel_launch(void* const* d_in, const int* in_sizes, int n_in,
                              void* d_out, int out_size, void* d_ws, size_t ws_size,
                              hipStream_t stream) {
  const void* hist = d_in[0];                  // (16,12,4096,1)
  const void* W0 = d_in[2];                    // (512,129,3,3)
  const void* b0 = d_in[3];
  const void* W1 = d_in[4];                    // (48,140,3,3)
  const void* b1 = d_in[5];

  char* ws = (char*)d_ws;
  const size_t PszB = (size_t)16 * 4096 * CS * 2;     // 20,971,520
  short* P[2] = {(short*)ws, (short*)(ws + PszB)};
  float* C0 = (float*)(ws + 2 * PszB);                // 33,554,432
  const size_t C0e = 2 * PszB + 33554432;
  float* C1 = (float*)(ws + C0e);                     // 3,145,728
  const size_t C1e = C0e + 3145728;
  short* zp = (short*)(ws + C1e);                     // 256 B zero page
  const size_t zpe = C1e + 256;                       // memset to here
  short* Xtap = (short*)(ws + zpe);                   // 12*65536*16*2 = 25,165,824
  const size_t Xte = zpe + (size_t)12 * 65536 * 16 * 2;
  short* Wp0 = (short*)(ws + Xte);                    // 512*1152*2 = 1,179,648
  const size_t W0e = Xte + (size_t)512 * KT0 * 2;
  short* Wx0 = (short*)(ws + W0e);                    // 512*16*2 = 16,384
  const size_t Wxe = W0e + 512 * 16 * 2;
  short* Wp1 = (short*)(ws + Wxe);                    // 48*1440*2 = 138,240
  const size_t W1e = Wxe + (size_t)48 * KTOT * 2;
  float* Bc0 = (float*)(ws + W1e);                    // 2048
  float* Bc1 = (float*)(ws + W1e + 2048);             // 192
  int* flag = (int*)(ws + W1e + 2048 + 192);          // total ~105 MiB

  hipMemsetAsync(ws, 0, zpe, stream);                 // P pair + C0 + C1 + zero page
  detect_dtype<<<1, 64, 0, stream>>>((const unsigned short*)W0, flag);
  canon_b<<<3, 256, 0, stream>>>(b0, b1, Bc0, Bc1, flag);
  prep_w0<<<(512 * KT0 + 255) / 256, 256, 0, stream>>>(W0, Wp0, flag);
  prep_wx<<<32, 256, 0, stream>>>(W0, Wx0, flag);
  prep_w1<<<(48 * KTOT + 255) / 256, 256, 0, stream>>>(W1, Wp1, flag);
  prep_xtap<<<3072, 256, 0, stream>>>(hist, Xtap, flag);

  for (int t = 0; t < 12; ++t) {
    gemm_gate0<<<1024, 256, 0, stream>>>(P[t & 1], P[(t + 1) & 1], Wp0, Wx0, Bc0, C0,
                                         Xtap, zp, t);
    gemm_gate1<<<512, 256, 0, stream>>>(P[(t + 1) & 1], P[t & 1], Wp1, Bc1, C1,
                                        d_out, zp, flag, t);
  }
}